// Round 5
// baseline (457.753 us; speedup 1.0000x reference)
//
#include <hip/hip_runtime.h>
#include <hip/hip_fp16.h>
#include <climits>
#include <math.h>

#define Bc   2
#define Tc   2048
#define Dc   2048
#define Nc   16
#define KHc  8
#define Hc   128
#define Sc   2048

constexpr float EPSc   = 1e-6f;
constexpr float SCALE2 = 0.1275174477984469f;     // (1/sqrt(128)) * log2(e)

typedef short short8 __attribute__((ext_vector_type(8)));
typedef _Float16 half8 __attribute__((ext_vector_type(8)));
typedef __fp16 fp16x2 __attribute__((ext_vector_type(2)));
typedef float float4v __attribute__((ext_vector_type(4)));

union U16x8 { uint4 u; short8 s8; half8 h8; unsigned short us[8]; };
union H2U  { fp16x2 h; unsigned u; };
union S8H8 { short8 s; half8 h; };

__device__ __forceinline__ unsigned short f2bf(float f) {
    union { float f; unsigned u; } v; v.f = f;
    unsigned r = v.u + 0x7FFFu + ((v.u >> 16) & 1u);
    return (unsigned short)(r >> 16);
}
__device__ __forceinline__ float bf2f(unsigned short u) {
    union { unsigned u; float f; } v; v.u = ((unsigned)u) << 16;
    return v.f;
}

// ---------------------------------------------------------------------------
// prep: fused meta + x-cast + 4 weight transposes (12 launches -> 1)
// ---------------------------------------------------------------------------
__device__ __forceinline__ void tc_body(const float* __restrict__ in,
                                        unsigned short* __restrict__ out,
                                        int R, int C, int bx, int by, int tid,
                                        float tile[32][33])
{
    int c0 = bx * 32, r0 = by * 32;
#pragma unroll
    for (int i = 0; i < 4; ++i) {
        int row = (tid >> 5) + i * 8, col = tid & 31;
        tile[row][col] = in[(size_t)(r0 + row) * C + c0 + col];
    }
    __syncthreads();
#pragma unroll
    for (int i = 0; i < 4; ++i) {
        int rowo = (tid >> 5) + i * 8, colo = tid & 31;
        out[(size_t)(c0 + rowo) * R + r0 + colo] = f2bf(tile[colo][rowo]);
    }
}

__global__ __launch_bounds__(256) void prep(const float* __restrict__ x,
                                            const float* __restrict__ qw,
                                            const float* __restrict__ kw,
                                            const float* __restrict__ vw,
                                            const float* __restrict__ ow,
                                            const int* __restrict__ seg,
                                            const int* __restrict__ start_ind,
                                            int* __restrict__ meta,
                                            unsigned short* __restrict__ xb,
                                            unsigned short* __restrict__ qkvwT,
                                            unsigned short* __restrict__ owT)
{
    __shared__ float tile[32][33];
    __shared__ int s_max, s_amax, s_nz;
    int id = blockIdx.x;
    int tid = threadIdx.x;

    if (id < Bc) {   // meta
        int b = id;
        if (tid == 0) { s_max = INT_MIN; s_amax = Tc; s_nz = Tc; }
        __syncthreads();
        int lmax = INT_MIN;
        for (int t = tid; t < Tc; t += 256) lmax = max(lmax, seg[b * Tc + t]);
        atomicMax(&s_max, lmax);
        __syncthreads();
        int mv = s_max;
        int lamax = Tc, lnz = Tc;
        for (int t = tid; t < Tc; t += 256) {
            int v = seg[b * Tc + t];
            if (v == mv) lamax = min(lamax, t);
            if (v != 0)  lnz   = min(lnz, t);
        }
        atomicMin(&s_amax, lamax);
        atomicMin(&s_nz, lnz);
        __syncthreads();
        if (tid == 0) {
            meta[b] = s_amax;
            int st = start_ind[b];
            meta[Bc + b] = (st < 0) ? s_nz : st;
        }
        return;
    }
    id -= Bc;
    if (id < 4096) {   // cast x
        size_t base = ((size_t)id * 256 + tid) * 8;
        float4 a = *(const float4*)&x[base];
        float4 b = *(const float4*)&x[base + 4];
        U16x8 o;
        o.us[0] = f2bf(a.x); o.us[1] = f2bf(a.y); o.us[2] = f2bf(a.z); o.us[3] = f2bf(a.w);
        o.us[4] = f2bf(b.x); o.us[5] = f2bf(b.y); o.us[6] = f2bf(b.z); o.us[7] = f2bf(b.w);
        *(uint4*)&xb[base] = o.u;
        return;
    }
    id -= 4096;
    if (id < 4096) { tc_body(qw, qkvwT, 2048, 2048, id & 63, id >> 6, tid, tile); return; }
    id -= 4096;
    if (id < 2048) { tc_body(kw, qkvwT + (size_t)2048 * 2048, 2048, 1024, id & 31, id >> 5, tid, tile); return; }
    id -= 2048;
    if (id < 2048) { tc_body(vw, qkvwT + (size_t)3072 * 2048, 2048, 1024, id & 31, id >> 5, tid, tile); return; }
    id -= 2048;
    tc_body(ow, owT, 2048, 2048, id & 63, id >> 6, tid, tile);
}

// ---------------------------------------------------------------------------
// 256x256 bf16 MFMA GEMM, 2-hazard schedule (R5 restructure of the 8-phase):
//   C[M,N] = A[M,K] * BT[N,K]^T.  512 thr = 8 waves (2M x 4N), BK=64.
//   LDS 128 KB ring: 2 buffers x (A 256x64 + B 256x64), tile kt <-> buf kt&1.
//   Per K-tile, only TWO hazards need sync:
//     PhaseA: read ALL 24 frags (A once, B once, no re-reads; 96 VGPR) with
//             32 MFMA (afl x B) compiler-interleaved; lgkmcnt(0); barrier
//             (all waves' reads of buf p complete).
//     PhaseB: stage tile kt+2 (A+B, 8 gload_lds) into buf p (fully consumed);
//             32 MFMA (afh x B) overlap the load issue; counted vmcnt(8)
//             (16 outstanding -> oldest 8 = tile kt+1 landed, kt+2 in
//             flight; vmcnt(0) only when nothing staged); barrier.
//   2 barriers/tile (was 8), 24 ds_reads/tile (was 32), prefetch dist = 2
//   tiles, never drain vmcnt in-loop. Same fragment addresses and same
//   per-element accumulation order as R4 -> bit-identical output.
// ---------------------------------------------------------------------------
__global__ __launch_bounds__(512, 2) void gemm256(const unsigned short* __restrict__ A,
                                                  const unsigned short* __restrict__ BT,
                                                  void* __restrict__ Cout,
                                                  int M, int N, int K, int out_fp32)
{
    __shared__ __align__(16) unsigned short As[2 * 16384];   // 64 KB
    __shared__ __align__(16) unsigned short Bs[2 * 16384];   // 64 KB

    int tid = threadIdx.x;
    int lane = tid & 63, w = tid >> 6;
    int quad = lane >> 4, l15 = lane & 15;

    // bijective XCD swizzle on linear block id (nwg % 8 == 0 for our shapes)
    int gx = gridDim.x;
    int nwg = gx * gridDim.y;
    int lin = blockIdx.y * gx + blockIdx.x;
    int swz = (lin & 7) * (nwg >> 3) + (lin >> 3);
    int bm = (swz / gx) * 256, bn = (swz % gx) * 256;

    int KT = K >> 6;

    // ---- staging source pointers (pre-swizzled column so LDS dest is linear)
    int colswz = (((lane & 7) ^ ((lane >> 3) & 7)) << 3);
    int r0 = (w * 2) * 8 + (lane >> 3);           // rows 0..127 within a half
    int r1 = (w * 2 + 1) * 8 + (lane >> 3);
    const unsigned short* Ab0 = A + (size_t)(bm + r0) * K + colswz;
    const unsigned short* Ab1 = A + (size_t)(bm + r1) * K + colswz;
    const unsigned short* Bb0 = BT + (size_t)(bn + r0) * K + colswz;
    const unsigned short* Bb1 = BT + (size_t)(bn + r1) * K + colswz;
    size_t hK = (size_t)128 * K;

    unsigned short* dA0 = As + (w * 2) * 512;     // + bufp*16384 + h*8192
    unsigned short* dA1 = As + (w * 2 + 1) * 512;
    unsigned short* dB0 = Bs + (w * 2) * 512;
    unsigned short* dB1 = Bs + (w * 2 + 1) * 512;

    auto stA = [&](int kt, int h, int bufp) __attribute__((always_inline)) {
        __builtin_amdgcn_global_load_lds(
            (__attribute__((address_space(1))) void*)(Ab0 + h * hK + (size_t)kt * 64),
            (__attribute__((address_space(3))) void*)(dA0 + bufp * 16384 + h * 8192), 16, 0, 0);
        __builtin_amdgcn_global_load_lds(
            (__attribute__((address_space(1))) void*)(Ab1 + h * hK + (size_t)kt * 64),
            (__attribute__((address_space(3))) void*)(dA1 + bufp * 16384 + h * 8192), 16, 0, 0);
    };
    auto stB = [&](int kt, int h, int bufp) __attribute__((always_inline)) {
        __builtin_amdgcn_global_load_lds(
            (__attribute__((address_space(1))) void*)(Bb0 + h * hK + (size_t)kt * 64),
            (__attribute__((address_space(3))) void*)(dB0 + bufp * 16384 + h * 8192), 16, 0, 0);
        __builtin_amdgcn_global_load_lds(
            (__attribute__((address_space(1))) void*)(Bb1 + h * hK + (size_t)kt * 64),
            (__attribute__((address_space(3))) void*)(dB1 + bufp * 16384 + h * 8192), 16, 0, 0);
    };

    // ---- fragment read bases (swizzled read: slot ^= row&7)
    int ards = (w >> 2) * 8192;                   // wave's A half
    int brds = (w & 3) * 4096;                    // wave's 64 B-rows
    int rowb = l15 * 64;
    int swA = l15 & 7;
    int cof0 = ((quad) ^ swA) << 3;               // kk=0 logical col quad*8
    int cof1 = ((4 + quad) ^ swA) << 3;           // kk=1

    float4v acc[8][4];
#pragma unroll
    for (int i = 0; i < 8; ++i)
#pragma unroll
        for (int j = 0; j < 4; ++j) acc[i][j] = (float4v)0.f;

    // ---- prologue: tile 0 -> buf0 (8 loads), tile 1 -> buf1 (8 loads)
    stA(0, 0, 0); stA(0, 1, 0); stB(0, 0, 0); stB(0, 1, 0);
    stA(1, 0, 1); stA(1, 1, 1); stB(1, 0, 1); stB(1, 1, 1);
    asm volatile("s_waitcnt vmcnt(8)" ::: "memory");   // tile 0 fully landed
    __builtin_amdgcn_s_barrier();
    asm volatile("" ::: "memory");

    auto ktile = [&](int kt, int bufp) __attribute__((always_inline)) {
        const unsigned short* ab = As + bufp * 16384 + ards + rowb;
        const unsigned short* bb = Bs + bufp * 16384 + brds + rowb;
        short8 afl[2][4], afh[2][4], bfa[2][2], bfb[2][2];

        // ---- PhaseA: read everything once (24 b128), 32 MFMA (afl x B)
#pragma unroll
        for (int mi = 0; mi < 4; ++mi) {
            afl[0][mi] = *(const short8*)&ab[mi * 1024 + cof0];
            afl[1][mi] = *(const short8*)&ab[mi * 1024 + cof1];
        }
#pragma unroll
        for (int ni = 0; ni < 2; ++ni) {
            bfa[0][ni] = *(const short8*)&bb[ni * 1024 + cof0];
            bfa[1][ni] = *(const short8*)&bb[ni * 1024 + cof1];
        }
#pragma unroll
        for (int ni = 0; ni < 2; ++ni) {
            bfb[0][ni] = *(const short8*)&bb[(2 + ni) * 1024 + cof0];
            bfb[1][ni] = *(const short8*)&bb[(2 + ni) * 1024 + cof1];
        }
#pragma unroll
        for (int mi = 0; mi < 4; ++mi) {
            afh[0][mi] = *(const short8*)&ab[(4 + mi) * 1024 + cof0];
            afh[1][mi] = *(const short8*)&ab[(4 + mi) * 1024 + cof1];
        }
        __builtin_amdgcn_s_setprio(1);
#pragma unroll
        for (int kk = 0; kk < 2; ++kk)
#pragma unroll
            for (int mi = 0; mi < 4; ++mi)
#pragma unroll
                for (int ni = 0; ni < 2; ++ni)
                    acc[mi][ni] = __builtin_amdgcn_mfma_f32_16x16x32_bf16(afl[kk][mi], bfa[kk][ni], acc[mi][ni], 0, 0, 0);
#pragma unroll
        for (int kk = 0; kk < 2; ++kk)
#pragma unroll
            for (int mi = 0; mi < 4; ++mi)
#pragma unroll
                for (int ni = 0; ni < 2; ++ni)
                    acc[mi][2 + ni] = __builtin_amdgcn_mfma_f32_16x16x32_bf16(afl[kk][mi], bfb[kk][ni], acc[mi][2 + ni], 0, 0, 0);
        __builtin_amdgcn_s_setprio(0);
        // hazard 1: all reads of buf p must be in regs before staging over it
        asm volatile("s_waitcnt lgkmcnt(0)" ::: "memory");
        __builtin_amdgcn_sched_barrier(0);
        __builtin_amdgcn_s_barrier();
        asm volatile("" ::: "memory");

        // ---- PhaseB: stage tile kt+2 -> buf p; 32 MFMA (afh x B) overlap
        bool sA = (kt + 2) < KT;
        if (sA) {
            stA(kt + 2, 0, bufp); stA(kt + 2, 1, bufp);
            stB(kt + 2, 0, bufp); stB(kt + 2, 1, bufp);
        }
        __builtin_amdgcn_s_setprio(1);
#pragma unroll
        for (int kk = 0; kk < 2; ++kk)
#pragma unroll
            for (int mi = 0; mi < 4; ++mi)
#pragma unroll
                for (int ni = 0; ni < 2; ++ni)
                    acc[4 + mi][ni] = __builtin_amdgcn_mfma_f32_16x16x32_bf16(afh[kk][mi], bfa[kk][ni], acc[4 + mi][ni], 0, 0, 0);
#pragma unroll
        for (int kk = 0; kk < 2; ++kk)
#pragma unroll
            for (int mi = 0; mi < 4; ++mi)
#pragma unroll
                for (int ni = 0; ni < 2; ++ni)
                    acc[4 + mi][2 + ni] = __builtin_amdgcn_mfma_f32_16x16x32_bf16(afh[kk][mi], bfb[kk][ni], acc[4 + mi][2 + ni], 0, 0, 0);
        __builtin_amdgcn_s_setprio(0);
        // hazard 2: tile kt+1 (oldest 8 of <=16 outstanding) landed
        if (sA) asm volatile("s_waitcnt vmcnt(8)" ::: "memory");
        else    asm volatile("s_waitcnt vmcnt(0)" ::: "memory");
        __builtin_amdgcn_sched_barrier(0);
        __builtin_amdgcn_s_barrier();
        asm volatile("" ::: "memory");
    };

    for (int kt = 0; kt < KT; kt += 2) {
        ktile(kt, 0);
        ktile(kt + 1, 1);
    }

    // ---- epilogue: per-wave 128x64 tile, C row = quad*4+reg, col = l15
    int wm = (w >> 2) * 128, wn = (w & 3) * 64;
#pragma unroll
    for (int mi = 0; mi < 8; ++mi)
#pragma unroll
        for (int ni = 0; ni < 4; ++ni)
#pragma unroll
            for (int reg = 0; reg < 4; ++reg) {
                int row = bm + wm + mi * 16 + quad * 4 + reg;
                int col = bn + wn + ni * 16 + l15;
                float v = acc[mi][ni][reg];
                if (out_fp32) ((float*)Cout)[(size_t)row * N + col] = v;
                else ((unsigned short*)Cout)[(size_t)row * N + col] = f2bf(v);
            }
}

// ---------------------------------------------------------------------------
// post: fused norm_rope (Q in-place, K -> Kall) + K-cache fill + V transpose
// ---------------------------------------------------------------------------
__global__ __launch_bounds__(256) void post(unsigned short* __restrict__ QKVh,
                                            unsigned short* __restrict__ Kall,
                                            unsigned short* __restrict__ Vt,
                                            const float* __restrict__ qw,
                                            const float* __restrict__ kw,
                                            const int* __restrict__ seg,
                                            const int* __restrict__ meta,
                                            const int* __restrict__ cur_ptr,
                                            const float* __restrict__ kc,
                                            const float* __restrict__ vc)
{
    int id = blockIdx.x;
    int tid = threadIdx.x;
    int cur = cur_ptr[0];

    if (id < 24576) {   // norm + rope
        int rowid = id * 4 + (tid >> 6);
        int lane = tid & 63;
        int hh = rowid % 24;
        int bt = rowid / 24;
        int t = bt & (Tc - 1);
        int b = bt >> 11;

        const unsigned short* in;
        unsigned short* out;
        const float* wt;
        if (hh < 16) {
            unsigned short* p = QKVh + (size_t)bt * 4096 + hh * Hc;
            in = p; out = p; wt = qw;
        } else {
            int kh = hh - 16;
            in = QKVh + (size_t)bt * 4096 + 2048 + kh * Hc;
            out = Kall + (((size_t)b * Sc + cur + t) * KHc + kh) * Hc;
            wt = kw;
        }
        float v1 = bf2f(in[lane]), v2 = bf2f(in[lane + 64]);
        float ssq = v1 * v1 + v2 * v2;
#pragma unroll
        for (int off = 1; off < 64; off <<= 1) ssq += __shfl_xor(ssq, off);
        float rinv = rsqrtf(ssq * (1.0f / Hc) + EPSc);

        int sg = seg[bt];
        long long pos = (sg != 0) ? (long long)(t - meta[b]) : (long long)(1 << 30);
        float posf = (float)(pos + (long long)cur);
        float inv_freq = exp2f(-(float)lane * (19.931568569324174f / 64.0f));
        float s, c;
        sincosf(posf * inv_freq, &s, &c);

        float n1 = wt[lane] * v1 * rinv;
        float n2 = wt[lane + 64] * v2 * rinv;
        out[lane]      = f2bf(n1 * c - n2 * s);
        out[lane + 64] = f2bf(n2 * c + n1 * s);
        return;
    }
    id -= 24576;
    if (id < 2048) {   // K cache fill
        size_t base = ((size_t)id * 256 + tid) * 8;
        int s = (int)((base >> 10) & (Sc - 1));
        if (s >= cur && s < cur + Tc) return;
        float4 a = *(const float4*)&kc[base];
        float4 b = *(const float4*)&kc[base + 4];
        U16x8 o;
        o.us[0] = f2bf(a.x); o.us[1] = f2bf(a.y); o.us[2] = f2bf(a.z); o.us[3] = f2bf(a.w);
        o.us[4] = f2bf(b.x); o.us[5] = f2bf(b.y); o.us[6] = f2bf(b.z); o.us[7] = f2bf(b.w);
        *(uint4*)&Kall[base] = o.u;
        return;
    }
    id -= 2048;
    {   // V transpose -> f16
        int gid = id * 256 + tid;
        int h  = gid & 127;
        int s8 = ((gid >> 7) & 255) * 8;
        int kh = (gid >> 15) & 7;
        int b  = gid >> 18;
        int curT = cur + Tc;
        unsigned short tmp[8];
#pragma unroll
        for (int e = 0; e < 8; ++e) {
            int s = s8 + e;
            float f;
            if (s >= cur && s < curT)
                f = bf2f(QKVh[(size_t)(b * Tc + (s - cur)) * 4096 + 3072 + kh * Hc + h]);
            else
                f = vc[((size_t)(b * Sc + s) * KHc + kh) * Hc + h];
            tmp[e] = __half_as_ushort(__float2half(f));
        }
        *(uint4*)&Vt[(((size_t)b * KHc + kh) * Hc + h) * Sc + s8] = *(uint4*)tmp;
    }
}

// ---------------------------------------------------------------------------
// MFMA flash attention, S^T formulation — 8-wave version (R3, proven):
//   128-row q-tiles, 512-thread blocks, each wave owns 16 q-rows.
//   LDS = Ks 16K + Vs 16K + Ps 16K = 48 KB.
// ---------------------------------------------------------------------------
__global__ __launch_bounds__(512, 4) void flash_mfma(const unsigned short* __restrict__ Qb,
                                                     const unsigned short* __restrict__ Kall,
                                                     const unsigned short* __restrict__ Vt,
                                                     const int* __restrict__ seg,
                                                     const int* __restrict__ meta,
                                                     const int* __restrict__ cur_ptr,
                                                     unsigned short* __restrict__ Ob)
{
    __shared__ __align__(16) unsigned short Ks[64 * 128];   // bf16 [s][h], swizzled
    __shared__ __align__(16) unsigned short Vs[128 * 64];   // f16  [h][s], swizzled
    __shared__ __align__(16) unsigned short Ps[128 * 64];   // f16  [q][s], XOR-swizzled

    int tid = threadIdx.x;
    int lane = tid & 63, w = tid >> 6;          // w in 0..7
    int quad = lane >> 4, l15 = lane & 15;
    int bid = blockIdx.x;
    int raw = bid & 15;
    int n  = (bid >> 4) & 15;
    int b  = bid >> 8;
    int qt = (b == 0) ? raw : (15 - raw);
    int kh = n >> 1;
    int cur = cur_ptr[0];
    int startb = meta[Bc + b];
    int curT = cur + Tc;
    int t0 = qt * 128 + w * 16;                 // this wave's 16 q-rows

    // Q fragments (B-operand layout == A layout: l15 -> q, quad*8+j -> h)
    short8 qf[4];
#pragma unroll
    for (int ks = 0; ks < 4; ++ks) {
        int row = t0 + l15;
        U16x8 uq;
        uq.u = *(const uint4*)&Qb[(size_t)(b * Tc + row) * 4096 + n * Hc + ks * 32 + quad * 8];
        qf[ks] = uq.s8;
    }

    // per-lane mask metadata (q = l15-indexed)
    int trow0 = t0 + l15;
    int sg0 = seg[b * Tc + trow0];
    int cls = (sg0 == 0) ? 0 : ((sg0 == 1) ? 1 : 2);
    int ct  = cur + trow0;
    unsigned long long mball = __ballot(cls == 1);
    bool allseg1 = (mball == 0xFFFFFFFFFFFFFFFFull);

    float lsum = 0.f;
    float4v oT[8];   // [htile]
#pragma unroll
    for (int i = 0; i < 8; ++i) oT[i] = (float4v)0.f;

    int s_end = min(Sc, cur + qt * 128 + 128);
    int nch = (s_end + 63) >> 6;

    // staging geometry (per wave: 2 K + 2 V global_load_lds per chunk)
    const size_t kstride = (size_t)KHc * Hc;
    const unsigned short* kptr[2];
    unsigned short* kdst[2];
#pragma unroll
    for (int i = 0; i < 2; ++i) {
        int j = w * 2 + i;                      // 0..15
        int row = j * 4 + (lane >> 4);          // 0..63
        int pl = lane & 15;
        int pg = pl ^ ((row >> 1) & 7);
        kptr[i] = Kall + (size_t)b * Sc * kstride + (size_t)row * kstride + kh * Hc + pg * 8;
        kdst[i] = Ks + j * 512;
    }
    const unsigned short* vptr[2];
    unsigned short* vdst[2];
#pragma unroll
    for (int i = 0; i < 2; ++i) {
        int j = w * 2 + i;                      // 0..15
        int h = j * 8 + (lane >> 3);            // 0..127
        int pl = lane & 7;
        int pg = pl ^ ((h >> 1) & 7);
        vptr[i] = Vt + ((size_t)b * KHc + kh) * (size_t)Hc * Sc + (size_t)h * Sc + pg * 8;
        vdst[i] = Vs + j * 512;
    }
    int sw3 = (l15 >> 1) & 7;
    int sw8 = l15 & 7;                          // Ps 16B-slot swizzle key (== row&7)
    unsigned short* psrow = Ps + (w * 16 + l15) * 64;   // this wave's q-row

    for (int c = 0; c < nch; ++c) {
        int s0 = c * 64;
#pragma unroll
        for (int i = 0; i < 2; ++i) {
            __builtin_amdgcn_global_load_lds(
                (__attribute__((address_space(1))) void*)(kptr[i] + (size_t)s0 * kstride),
                (__attribute__((address_space(3))) void*)kdst[i], 16, 0, 0);
            __builtin_amdgcn_global_load_lds(
                (__attribute__((address_space(1))) void*)(vptr[i] + s0),
                (__attribute__((address_space(3))) void*)vdst[i], 16, 0, 0);
        }
        __syncthreads();

        // S^T = K·Q^T : st[stile], row=s, col=q
        float4v st[4];
#pragma unroll
        for (int i = 0; i < 4; ++i) st[i] = (float4v)0.f;
        __builtin_amdgcn_s_setprio(1);
#pragma unroll
        for (int ks = 0; ks < 4; ++ks) {
#pragma unroll
            for (int stile = 0; stile < 4; ++stile) {
                short8 kf = *(const short8*)&Ks[(stile * 16 + l15) * 128 + ((ks * 4 + quad) ^ sw3) * 8];
                st[stile] = __builtin_amdgcn_mfma_f32_16x16x32_bf16(kf, qf[ks], st[stile], 0, 0, 0);
            }
        }
        __builtin_amdgcn_s_setprio(0);

        bool fullok = allseg1 && (s0 >= startb) && (s0 + 63 <= cur + t0) && (s0 + 63 < curT);

        // softmax: p = exp2(score*SCALE2); pack 4 s-consecutive f16 -> uint2 store
#pragma unroll
        for (int stile = 0; stile < 4; ++stile) {
            float p0, p1, p2, p3;
            if (fullok) {
                p0 = exp2f(st[stile][0] * SCALE2);
                p1 = exp2f(st[stile][1] * SCALE2);
                p2 = exp2f(st[stile][2] * SCALE2);
                p3 = exp2f(st[stile][3] * SCALE2);
            } else {
                float pp[4];
#pragma unroll
                for (int reg = 0; reg < 4; ++reg) {
                    int s = s0 + stile * 16 + quad * 4 + reg;
                    int kvseg = (s >= startb && s < curT) ? 1 : 0;
                    bool ok = (s <= ct) && (cls == kvseg);
                    pp[reg] = exp2f(ok ? st[stile][reg] * SCALE2 : -1e30f);
                }
                p0 = pp[0]; p1 = pp[1]; p2 = pp[2]; p3 = pp[3];
            }
            lsum += (p0 + p1) + (p2 + p3);
            H2U a, d;
            a.h = __builtin_amdgcn_cvt_pkrtz(p0, p1);
            d.h = __builtin_amdgcn_cvt_pkrtz(p2, p3);
            uint2 pk; pk.x = a.u; pk.y = d.u;
            // 16B slot = (stile*2 + (quad>>1)) ^ sw8 ; uint2 in half (quad&1)
            *(uint2*)&psrow[(((stile * 2 + (quad >> 1)) ^ sw8) << 3) + (quad & 1) * 4] = pk;
        }

        // O^T += V^T · P^T   (A = Vs f16, B = Ps f16) — own wave's Ps row only
        __builtin_amdgcn_s_setprio(1);
#pragma unroll
        for (int kk = 0; kk < 2; ++kk) {
            S8H8 pf;
            pf.s = *(const short8*)&psrow[((kk * 4 + quad) ^ sw8) << 3];
#pragma unroll
            for (int htile = 0; htile < 8; ++htile) {
                S8H8 vf;
                vf.s = *(const short8*)&Vs[(htile * 16 + l15) * 64 + ((kk * 4 + quad) ^ sw3) * 8];
                oT[htile] = __builtin_amdgcn_mfma_f32_16x16x32_f16(vf.h, pf.h, oT[htile], 0, 0, 0);
            }
        }
        __builtin_amdgcn_s_setprio(0);

        __syncthreads();   // WAR: next staging overwrites Ks/Vs
    }

    // l: sum across the 4 quads holding the same q (xor 16, 32)
    float l = lsum;
    l += __shfl_xor(l, 16);
    l += __shfl_xor(l, 32);
    float linv = (l > 0.f) ? (1.0f / l) : 0.f;

    // epilogue: O^T col=q(l15), row=h(quad*4+reg) -> packed bf16 stores
    {
        int trow = t0 + l15;
        size_t base = ((size_t)(b * Tc + trow) * Nc + n) * Hc;
#pragma unroll
        for (int htile = 0; htile < 8; ++htile) {
            float4v v = oT[htile];
            unsigned short r0 = f2bf(v[0] * linv);
            unsigned short r1 = f2bf(v[1] * linv);
            unsigned short r2 = f2bf(v[2] * linv);
            unsigned short r3 = f2bf(v[3] * linv);
            uint2 pk;
            pk.x = (unsigned)r0 | ((unsigned)r1 << 16);
            pk.y = (unsigned)r2 | ((unsigned)r3 << 16);
            *(uint2*)&Ob[base + htile * 16 + quad * 4] = pk;
        }
    }
}

// ---------------------------------------------------------------------------
extern "C" void kernel_launch(void* const* d_in, const int* in_sizes, int n_in,
                              void* d_out, int out_size, void* d_ws, size_t ws_size,
                              hipStream_t stream)
{
    const float* x        = (const float*)d_in[0];
    const float* q_w      = (const float*)d_in[1];
    const float* k_w      = (const float*)d_in[2];
    const float* v_w      = (const float*)d_in[3];
    const float* o_w      = (const float*)d_in[4];
    const float* q_norm_w = (const float*)d_in[5];
    const float* k_norm_w = (const float*)d_in[6];
    const float* k_cache  = (const float*)d_in[7];
    const float* v_cache  = (const float*)d_in[8];
    const int*   seg      = (const int*)d_in[9];
    const int*   startind = (const int*)d_in[10];
    const int*   cur_ptr  = (const int*)d_in[11];
    (void)in_sizes; (void)n_in; (void)out_size; (void)ws_size;

    char* base = (char*)d_ws;
    int* meta = (int*)base;                                          //      1024 B
    unsigned short* QKVh = (unsigned short*)(base + 1024);           // 33.55 MB [4096][4096]
    unsigned short* Kall = (unsigned short*)(base + 33555456);       //  8.39 MB bf16 [B][S][KH][H]
    unsigned short* Vt   = (unsigned short*)(base + 41944064);       //  8.39 MB f16  [B][KH][H][S]
    unsigned short* xb   = (unsigned short*)(base + 50332672);       // 16.78 MB; reused as Ob
    unsigned short* qkvwT= (unsigned short*)(base + 67109888);       // 16.78 MB [4096][2048]
    unsigned short* owT  = (unsigned short*)(base + 83887104);       //  8.39 MB [2048][2048]
    unsigned short* Ob   = xb;

    // 1) fused prep: meta + cast + 4 transposes
    prep<<<Bc + 4096 + 4096 + 2048 + 2048 + 4096, 256, 0, stream>>>(
        x, q_w, k_w, v_w, o_w, seg, startind, meta, xb, qkvwT, owT);

    // 2) fused QKV projection: [4096 x 2048] @ [2048 x 4096] (256^2 2-hazard)
    gemm256<<<dim3(16, 16), 512, 0, stream>>>(xb, qkvwT, QKVh, Bc * Tc, 4096, Dc, 0);

    // 3) fused post: norm+rope, K-cache fill, V transpose (f16)
    post<<<24576 + 2048 + 2048, 256, 0, stream>>>(QKVh, Kall, Vt,
        q_norm_w, k_norm_w, seg, meta, cur_ptr, k_cache, v_cache);

    // 4) flash attention: 128-row tiles, 8-wave blocks (2 waves/SIMD min)
    flash_mfma<<<Bc * Nc * (Tc / 128), 512, 0, stream>>>(QKVh, Kall, Vt, seg, meta, cur_ptr, Ob);

    // 5) O projection -> fp32 out (256^2 2-hazard)
    gemm256<<<dim3(8, 16), 512, 0, stream>>>(Ob, owT, d_out, Bc * Tc, Dc, Nc * Hc, 1);
}

// Round 6
// 393.268 us; speedup vs baseline: 1.1640x; 1.1640x over previous
//
#include <hip/hip_runtime.h>
#include <hip/hip_fp16.h>
#include <climits>
#include <math.h>

#define Bc   2
#define Tc   2048
#define Dc   2048
#define Nc   16
#define KHc  8
#define Hc   128
#define Sc   2048

constexpr float EPSc   = 1e-6f;
constexpr float SCALE2 = 0.1275174477984469f;     // (1/sqrt(128)) * log2(e)

typedef short short8 __attribute__((ext_vector_type(8)));
typedef _Float16 half8 __attribute__((ext_vector_type(8)));
typedef __fp16 fp16x2 __attribute__((ext_vector_type(2)));
typedef float float4v __attribute__((ext_vector_type(4)));

union U16x8 { uint4 u; short8 s8; half8 h8; unsigned short us[8]; };
union H2U  { fp16x2 h; unsigned u; };
union S8H8 { short8 s; half8 h; };

__device__ __forceinline__ unsigned short f2bf(float f) {
    union { float f; unsigned u; } v; v.f = f;
    unsigned r = v.u + 0x7FFFu + ((v.u >> 16) & 1u);
    return (unsigned short)(r >> 16);
}
__device__ __forceinline__ float bf2f(unsigned short u) {
    union { unsigned u; float f; } v; v.u = ((unsigned)u) << 16;
    return v.f;
}

// ---------------------------------------------------------------------------
// prep: fused meta + x-cast + 4 weight transposes (12 launches -> 1)
// ---------------------------------------------------------------------------
__device__ __forceinline__ void tc_body(const float* __restrict__ in,
                                        unsigned short* __restrict__ out,
                                        int R, int C, int bx, int by, int tid,
                                        float tile[32][33])
{
    int c0 = bx * 32, r0 = by * 32;
#pragma unroll
    for (int i = 0; i < 4; ++i) {
        int row = (tid >> 5) + i * 8, col = tid & 31;
        tile[row][col] = in[(size_t)(r0 + row) * C + c0 + col];
    }
    __syncthreads();
#pragma unroll
    for (int i = 0; i < 4; ++i) {
        int rowo = (tid >> 5) + i * 8, colo = tid & 31;
        out[(size_t)(c0 + rowo) * R + r0 + colo] = f2bf(tile[colo][rowo]);
    }
}

__global__ __launch_bounds__(256) void prep(const float* __restrict__ x,
                                            const float* __restrict__ qw,
                                            const float* __restrict__ kw,
                                            const float* __restrict__ vw,
                                            const float* __restrict__ ow,
                                            const int* __restrict__ seg,
                                            const int* __restrict__ start_ind,
                                            int* __restrict__ meta,
                                            unsigned short* __restrict__ xb,
                                            unsigned short* __restrict__ qkvwT,
                                            unsigned short* __restrict__ owT)
{
    __shared__ float tile[32][33];
    __shared__ int s_max, s_amax, s_nz;
    int id = blockIdx.x;
    int tid = threadIdx.x;

    if (id < Bc) {   // meta
        int b = id;
        if (tid == 0) { s_max = INT_MIN; s_amax = Tc; s_nz = Tc; }
        __syncthreads();
        int lmax = INT_MIN;
        for (int t = tid; t < Tc; t += 256) lmax = max(lmax, seg[b * Tc + t]);
        atomicMax(&s_max, lmax);
        __syncthreads();
        int mv = s_max;
        int lamax = Tc, lnz = Tc;
        for (int t = tid; t < Tc; t += 256) {
            int v = seg[b * Tc + t];
            if (v == mv) lamax = min(lamax, t);
            if (v != 0)  lnz   = min(lnz, t);
        }
        atomicMin(&s_amax, lamax);
        atomicMin(&s_nz, lnz);
        __syncthreads();
        if (tid == 0) {
            meta[b] = s_amax;
            int st = start_ind[b];
            meta[Bc + b] = (st < 0) ? s_nz : st;
        }
        return;
    }
    id -= Bc;
    if (id < 4096) {   // cast x
        size_t base = ((size_t)id * 256 + tid) * 8;
        float4 a = *(const float4*)&x[base];
        float4 b = *(const float4*)&x[base + 4];
        U16x8 o;
        o.us[0] = f2bf(a.x); o.us[1] = f2bf(a.y); o.us[2] = f2bf(a.z); o.us[3] = f2bf(a.w);
        o.us[4] = f2bf(b.x); o.us[5] = f2bf(b.y); o.us[6] = f2bf(b.z); o.us[7] = f2bf(b.w);
        *(uint4*)&xb[base] = o.u;
        return;
    }
    id -= 4096;
    if (id < 4096) { tc_body(qw, qkvwT, 2048, 2048, id & 63, id >> 6, tid, tile); return; }
    id -= 4096;
    if (id < 2048) { tc_body(kw, qkvwT + (size_t)2048 * 2048, 2048, 1024, id & 31, id >> 5, tid, tile); return; }
    id -= 2048;
    if (id < 2048) { tc_body(vw, qkvwT + (size_t)3072 * 2048, 2048, 1024, id & 31, id >> 5, tid, tile); return; }
    id -= 2048;
    tc_body(ow, owT, 2048, 2048, id & 63, id >> 6, tid, tile);
}

// ---------------------------------------------------------------------------
// 256x256 bf16 MFMA GEMM, 2-barrier schedule with register diet (R6):
//   C[M,N] = A[M,K] * BT[N,K]^T.  512 thr = 8 waves (2M x 4N), BK=64.
//   gfx950 unified RF: acc = 128 AGPR -> <=128 arch VGPR at 2 waves/SIMD.
//   R5 failed by holding 24 frags live up-front (spill, WRITE_SIZE 175MB).
//   R6: staggered reads so A-lo frags die before A-hi is read; bfa/bfb
//   stay live across the mid barrier (24 ds_reads/tile, no re-reads).
//   Staging = R4's proven split: chunk1 stages B(kt+1)->buf p^1 (its old
//   tile B(kt-1) was fully read before the tile-boundary barrier); chunk2
//   stages A(kt+2)->buf p (A-reads certified by mid lgkmcnt(0)+barrier).
//   End-of-tile s_waitcnt vmcnt(4): outstanding = A(kt+1)4+B(kt+1)4+
//   A(kt+2)4 = 12 -> oldest 8 (= next tile's A+B) landed, A(kt+2) flying.
//   2 barriers/tile (was 8 in R4). Accumulation order per C element
//   unchanged (kk0,kk1 per kt, kt ascending) -> bit-identical output.
// ---------------------------------------------------------------------------
__global__ __launch_bounds__(512, 2) void gemm256(const unsigned short* __restrict__ A,
                                                  const unsigned short* __restrict__ BT,
                                                  void* __restrict__ Cout,
                                                  int M, int N, int K, int out_fp32)
{
    __shared__ __align__(16) unsigned short As[2 * 16384];   // 64 KB
    __shared__ __align__(16) unsigned short Bs[2 * 16384];   // 64 KB

    int tid = threadIdx.x;
    int lane = tid & 63, w = tid >> 6;
    int quad = lane >> 4, l15 = lane & 15;

    // bijective XCD swizzle on linear block id (nwg % 8 == 0 for our shapes)
    int gx = gridDim.x;
    int nwg = gx * gridDim.y;
    int lin = blockIdx.y * gx + blockIdx.x;
    int swz = (lin & 7) * (nwg >> 3) + (lin >> 3);
    int bm = (swz / gx) * 256, bn = (swz % gx) * 256;

    int KT = K >> 6;

    // ---- staging source (pre-swizzled column so LDS dest stays linear)
    int colswz = (((lane & 7) ^ ((lane >> 3) & 7)) << 3);
    int r0 = (w * 2) * 8 + (lane >> 3);           // rows 0..127 within a half
    const unsigned short* Ab0 = A + (size_t)(bm + r0) * K + colswz;
    const unsigned short* Bb0 = BT + (size_t)(bn + r0) * K + colswz;
    size_t rowK8 = (size_t)8 * K;                 // +8 rows (r1 = r0+8)
    size_t hK = (size_t)128 * K;                  // half stride

    unsigned short* dA0 = As + (w * 2) * 512;     // + bufp*16384 + h*8192 (+512 for r1)
    unsigned short* dB0 = Bs + (w * 2) * 512;

    auto stA = [&](int kt, int bufp) __attribute__((always_inline)) {
#pragma unroll
        for (int h = 0; h < 2; ++h) {
            __builtin_amdgcn_global_load_lds(
                (__attribute__((address_space(1))) void*)(Ab0 + h * hK + (size_t)kt * 64),
                (__attribute__((address_space(3))) void*)(dA0 + bufp * 16384 + h * 8192), 16, 0, 0);
            __builtin_amdgcn_global_load_lds(
                (__attribute__((address_space(1))) void*)(Ab0 + h * hK + rowK8 + (size_t)kt * 64),
                (__attribute__((address_space(3))) void*)(dA0 + bufp * 16384 + h * 8192 + 512), 16, 0, 0);
        }
    };
    auto stB = [&](int kt, int bufp) __attribute__((always_inline)) {
#pragma unroll
        for (int h = 0; h < 2; ++h) {
            __builtin_amdgcn_global_load_lds(
                (__attribute__((address_space(1))) void*)(Bb0 + h * hK + (size_t)kt * 64),
                (__attribute__((address_space(3))) void*)(dB0 + bufp * 16384 + h * 8192), 16, 0, 0);
            __builtin_amdgcn_global_load_lds(
                (__attribute__((address_space(1))) void*)(Bb0 + h * hK + rowK8 + (size_t)kt * 64),
                (__attribute__((address_space(3))) void*)(dB0 + bufp * 16384 + h * 8192 + 512), 16, 0, 0);
        }
    };

    // ---- fragment read bases (swizzled read: slot ^= row&7)
    int ards = (w >> 2) * 8192;                   // wave's A half
    int brds = (w & 3) * 4096;                    // wave's 64 B-rows
    int rowb = l15 * 64;
    int swA = l15 & 7;
    int cof0 = ((quad) ^ swA) << 3;               // kk=0 logical col quad*8
    int cof1 = ((4 + quad) ^ swA) << 3;           // kk=1

    float4v acc[8][4];
#pragma unroll
    for (int i = 0; i < 8; ++i)
#pragma unroll
        for (int j = 0; j < 4; ++j) acc[i][j] = (float4v)0.f;

    // ---- prologue: tile0 -> buf0 (8 loads), A(1) -> buf1 (4 loads)
    stA(0, 0); stB(0, 0);
    stA(1, 1);
    asm volatile("s_waitcnt vmcnt(4)" ::: "memory");   // tile 0 fully landed
    __builtin_amdgcn_s_barrier();
    asm volatile("" ::: "memory");

    auto ktile = [&](int kt, int bufp) __attribute__((always_inline)) {
        const unsigned short* ab = As + bufp * 16384 + ards + rowb;
        const unsigned short* bb = Bs + bufp * 16384 + brds + rowb;
        short8 afl[2][4], afh[2][4], bfa[2][2], bfb[2][2];

        // ---- chunk1: stage B(kt+1)->buf p^1; staggered reads + 32 MFMA
        if (kt + 1 < KT) stB(kt + 1, bufp ^ 1);
#pragma unroll
        for (int mi = 0; mi < 4; ++mi) {
            afl[0][mi] = *(const short8*)&ab[mi * 1024 + cof0];
            afl[1][mi] = *(const short8*)&ab[mi * 1024 + cof1];
        }
#pragma unroll
        for (int ni = 0; ni < 2; ++ni) {
            bfa[0][ni] = *(const short8*)&bb[ni * 1024 + cof0];
            bfa[1][ni] = *(const short8*)&bb[ni * 1024 + cof1];
        }
        __builtin_amdgcn_s_setprio(1);
#pragma unroll
        for (int kk = 0; kk < 2; ++kk)
#pragma unroll
            for (int mi = 0; mi < 4; ++mi)
#pragma unroll
                for (int ni = 0; ni < 2; ++ni)
                    acc[mi][ni] = __builtin_amdgcn_mfma_f32_16x16x32_bf16(afl[kk][mi], bfa[kk][ni], acc[mi][ni], 0, 0, 0);
        __builtin_amdgcn_s_setprio(0);
#pragma unroll
        for (int ni = 0; ni < 2; ++ni) {
            bfb[0][ni] = *(const short8*)&bb[(2 + ni) * 1024 + cof0];
            bfb[1][ni] = *(const short8*)&bb[(2 + ni) * 1024 + cof1];
        }
        __builtin_amdgcn_s_setprio(1);
#pragma unroll
        for (int kk = 0; kk < 2; ++kk)
#pragma unroll
            for (int mi = 0; mi < 4; ++mi)
#pragma unroll
                for (int ni = 0; ni < 2; ++ni)
                    acc[mi][2 + ni] = __builtin_amdgcn_mfma_f32_16x16x32_bf16(afl[kk][mi], bfb[kk][ni], acc[mi][2 + ni], 0, 0, 0);
        __builtin_amdgcn_s_setprio(0);
        // afl dead from here; read A-hi (regalloc can reuse afl's registers)
#pragma unroll
        for (int mi = 0; mi < 4; ++mi) {
            afh[0][mi] = *(const short8*)&ab[(4 + mi) * 1024 + cof0];
            afh[1][mi] = *(const short8*)&ab[(4 + mi) * 1024 + cof1];
        }
        // hazard 1: all LDS reads of buf p in regs before A-stage overwrites
        asm volatile("s_waitcnt lgkmcnt(0)" ::: "memory");
        __builtin_amdgcn_sched_barrier(0);
        __builtin_amdgcn_s_barrier();
        asm volatile("" ::: "memory");

        // ---- chunk2: stage A(kt+2)->buf p; 32 MFMA (afh x bfa/bfb)
        bool sA = (kt + 2) < KT;
        if (sA) stA(kt + 2, bufp);
        __builtin_amdgcn_s_setprio(1);
#pragma unroll
        for (int kk = 0; kk < 2; ++kk)
#pragma unroll
            for (int mi = 0; mi < 4; ++mi)
#pragma unroll
                for (int ni = 0; ni < 2; ++ni)
                    acc[4 + mi][ni] = __builtin_amdgcn_mfma_f32_16x16x32_bf16(afh[kk][mi], bfa[kk][ni], acc[4 + mi][ni], 0, 0, 0);
#pragma unroll
        for (int kk = 0; kk < 2; ++kk)
#pragma unroll
            for (int mi = 0; mi < 4; ++mi)
#pragma unroll
                for (int ni = 0; ni < 2; ++ni)
                    acc[4 + mi][2 + ni] = __builtin_amdgcn_mfma_f32_16x16x32_bf16(afh[kk][mi], bfb[kk][ni], acc[4 + mi][2 + ni], 0, 0, 0);
        __builtin_amdgcn_s_setprio(0);
        // hazard 2: next tile's A+B (oldest 8 of <=12 outstanding) landed
        if (sA) asm volatile("s_waitcnt vmcnt(4)" ::: "memory");
        else    asm volatile("s_waitcnt vmcnt(0)" ::: "memory");
        __builtin_amdgcn_sched_barrier(0);
        __builtin_amdgcn_s_barrier();
        asm volatile("" ::: "memory");
    };

    for (int kt = 0; kt < KT; kt += 2) {
        ktile(kt, 0);
        ktile(kt + 1, 1);
    }

    // ---- epilogue: per-wave 128x64 tile, C row = quad*4+reg, col = l15
    int wm = (w >> 2) * 128, wn = (w & 3) * 64;
#pragma unroll
    for (int mi = 0; mi < 8; ++mi)
#pragma unroll
        for (int ni = 0; ni < 4; ++ni)
#pragma unroll
            for (int reg = 0; reg < 4; ++reg) {
                int row = bm + wm + mi * 16 + quad * 4 + reg;
                int col = bn + wn + ni * 16 + l15;
                float v = acc[mi][ni][reg];
                if (out_fp32) ((float*)Cout)[(size_t)row * N + col] = v;
                else ((unsigned short*)Cout)[(size_t)row * N + col] = f2bf(v);
            }
}

// ---------------------------------------------------------------------------
// post: fused norm_rope (Q in-place, K -> Kall) + K-cache fill + V transpose
// ---------------------------------------------------------------------------
__global__ __launch_bounds__(256) void post(unsigned short* __restrict__ QKVh,
                                            unsigned short* __restrict__ Kall,
                                            unsigned short* __restrict__ Vt,
                                            const float* __restrict__ qw,
                                            const float* __restrict__ kw,
                                            const int* __restrict__ seg,
                                            const int* __restrict__ meta,
                                            const int* __restrict__ cur_ptr,
                                            const float* __restrict__ kc,
                                            const float* __restrict__ vc)
{
    int id = blockIdx.x;
    int tid = threadIdx.x;
    int cur = cur_ptr[0];

    if (id < 24576) {   // norm + rope
        int rowid = id * 4 + (tid >> 6);
        int lane = tid & 63;
        int hh = rowid % 24;
        int bt = rowid / 24;
        int t = bt & (Tc - 1);
        int b = bt >> 11;

        const unsigned short* in;
        unsigned short* out;
        const float* wt;
        if (hh < 16) {
            unsigned short* p = QKVh + (size_t)bt * 4096 + hh * Hc;
            in = p; out = p; wt = qw;
        } else {
            int kh = hh - 16;
            in = QKVh + (size_t)bt * 4096 + 2048 + kh * Hc;
            out = Kall + (((size_t)b * Sc + cur + t) * KHc + kh) * Hc;
            wt = kw;
        }
        float v1 = bf2f(in[lane]), v2 = bf2f(in[lane + 64]);
        float ssq = v1 * v1 + v2 * v2;
#pragma unroll
        for (int off = 1; off < 64; off <<= 1) ssq += __shfl_xor(ssq, off);
        float rinv = rsqrtf(ssq * (1.0f / Hc) + EPSc);

        int sg = seg[bt];
        long long pos = (sg != 0) ? (long long)(t - meta[b]) : (long long)(1 << 30);
        float posf = (float)(pos + (long long)cur);
        float inv_freq = exp2f(-(float)lane * (19.931568569324174f / 64.0f));
        float s, c;
        sincosf(posf * inv_freq, &s, &c);

        float n1 = wt[lane] * v1 * rinv;
        float n2 = wt[lane + 64] * v2 * rinv;
        out[lane]      = f2bf(n1 * c - n2 * s);
        out[lane + 64] = f2bf(n2 * c + n1 * s);
        return;
    }
    id -= 24576;
    if (id < 2048) {   // K cache fill
        size_t base = ((size_t)id * 256 + tid) * 8;
        int s = (int)((base >> 10) & (Sc - 1));
        if (s >= cur && s < cur + Tc) return;
        float4 a = *(const float4*)&kc[base];
        float4 b = *(const float4*)&kc[base + 4];
        U16x8 o;
        o.us[0] = f2bf(a.x); o.us[1] = f2bf(a.y); o.us[2] = f2bf(a.z); o.us[3] = f2bf(a.w);
        o.us[4] = f2bf(b.x); o.us[5] = f2bf(b.y); o.us[6] = f2bf(b.z); o.us[7] = f2bf(b.w);
        *(uint4*)&Kall[base] = o.u;
        return;
    }
    id -= 2048;
    {   // V transpose -> f16
        int gid = id * 256 + tid;
        int h  = gid & 127;
        int s8 = ((gid >> 7) & 255) * 8;
        int kh = (gid >> 15) & 7;
        int b  = gid >> 18;
        int curT = cur + Tc;
        unsigned short tmp[8];
#pragma unroll
        for (int e = 0; e < 8; ++e) {
            int s = s8 + e;
            float f;
            if (s >= cur && s < curT)
                f = bf2f(QKVh[(size_t)(b * Tc + (s - cur)) * 4096 + 3072 + kh * Hc + h]);
            else
                f = vc[((size_t)(b * Sc + s) * KHc + kh) * Hc + h];
            tmp[e] = __half_as_ushort(__float2half(f));
        }
        *(uint4*)&Vt[(((size_t)b * KHc + kh) * Hc + h) * Sc + s8] = *(uint4*)tmp;
    }
}

// ---------------------------------------------------------------------------
// MFMA flash attention, S^T formulation — 8-wave version (R3, proven):
//   128-row q-tiles, 512-thread blocks, each wave owns 16 q-rows.
//   LDS = Ks 16K + Vs 16K + Ps 16K = 48 KB.
// ---------------------------------------------------------------------------
__global__ __launch_bounds__(512, 4) void flash_mfma(const unsigned short* __restrict__ Qb,
                                                     const unsigned short* __restrict__ Kall,
                                                     const unsigned short* __restrict__ Vt,
                                                     const int* __restrict__ seg,
                                                     const int* __restrict__ meta,
                                                     const int* __restrict__ cur_ptr,
                                                     unsigned short* __restrict__ Ob)
{
    __shared__ __align__(16) unsigned short Ks[64 * 128];   // bf16 [s][h], swizzled
    __shared__ __align__(16) unsigned short Vs[128 * 64];   // f16  [h][s], swizzled
    __shared__ __align__(16) unsigned short Ps[128 * 64];   // f16  [q][s], XOR-swizzled

    int tid = threadIdx.x;
    int lane = tid & 63, w = tid >> 6;          // w in 0..7
    int quad = lane >> 4, l15 = lane & 15;
    int bid = blockIdx.x;
    int raw = bid & 15;
    int n  = (bid >> 4) & 15;
    int b  = bid >> 8;
    int qt = (b == 0) ? raw : (15 - raw);
    int kh = n >> 1;
    int cur = cur_ptr[0];
    int startb = meta[Bc + b];
    int curT = cur + Tc;
    int t0 = qt * 128 + w * 16;                 // this wave's 16 q-rows

    // Q fragments (B-operand layout == A layout: l15 -> q, quad*8+j -> h)
    short8 qf[4];
#pragma unroll
    for (int ks = 0; ks < 4; ++ks) {
        int row = t0 + l15;
        U16x8 uq;
        uq.u = *(const uint4*)&Qb[(size_t)(b * Tc + row) * 4096 + n * Hc + ks * 32 + quad * 8];
        qf[ks] = uq.s8;
    }

    // per-lane mask metadata (q = l15-indexed)
    int trow0 = t0 + l15;
    int sg0 = seg[b * Tc + trow0];
    int cls = (sg0 == 0) ? 0 : ((sg0 == 1) ? 1 : 2);
    int ct  = cur + trow0;
    unsigned long long mball = __ballot(cls == 1);
    bool allseg1 = (mball == 0xFFFFFFFFFFFFFFFFull);

    float lsum = 0.f;
    float4v oT[8];   // [htile]
#pragma unroll
    for (int i = 0; i < 8; ++i) oT[i] = (float4v)0.f;

    int s_end = min(Sc, cur + qt * 128 + 128);
    int nch = (s_end + 63) >> 6;

    // staging geometry (per wave: 2 K + 2 V global_load_lds per chunk)
    const size_t kstride = (size_t)KHc * Hc;
    const unsigned short* kptr[2];
    unsigned short* kdst[2];
#pragma unroll
    for (int i = 0; i < 2; ++i) {
        int j = w * 2 + i;                      // 0..15
        int row = j * 4 + (lane >> 4);          // 0..63
        int pl = lane & 15;
        int pg = pl ^ ((row >> 1) & 7);
        kptr[i] = Kall + (size_t)b * Sc * kstride + (size_t)row * kstride + kh * Hc + pg * 8;
        kdst[i] = Ks + j * 512;
    }
    const unsigned short* vptr[2];
    unsigned short* vdst[2];
#pragma unroll
    for (int i = 0; i < 2; ++i) {
        int j = w * 2 + i;                      // 0..15
        int h = j * 8 + (lane >> 3);            // 0..127
        int pl = lane & 7;
        int pg = pl ^ ((h >> 1) & 7);
        vptr[i] = Vt + ((size_t)b * KHc + kh) * (size_t)Hc * Sc + (size_t)h * Sc + pg * 8;
        vdst[i] = Vs + j * 512;
    }
    int sw3 = (l15 >> 1) & 7;
    int sw8 = l15 & 7;                          // Ps 16B-slot swizzle key (== row&7)
    unsigned short* psrow = Ps + (w * 16 + l15) * 64;   // this wave's q-row

    for (int c = 0; c < nch; ++c) {
        int s0 = c * 64;
#pragma unroll
        for (int i = 0; i < 2; ++i) {
            __builtin_amdgcn_global_load_lds(
                (__attribute__((address_space(1))) void*)(kptr[i] + (size_t)s0 * kstride),
                (__attribute__((address_space(3))) void*)kdst[i], 16, 0, 0);
            __builtin_amdgcn_global_load_lds(
                (__attribute__((address_space(1))) void*)(vptr[i] + s0),
                (__attribute__((address_space(3))) void*)vdst[i], 16, 0, 0);
        }
        __syncthreads();

        // S^T = K·Q^T : st[stile], row=s, col=q
        float4v st[4];
#pragma unroll
        for (int i = 0; i < 4; ++i) st[i] = (float4v)0.f;
        __builtin_amdgcn_s_setprio(1);
#pragma unroll
        for (int ks = 0; ks < 4; ++ks) {
#pragma unroll
            for (int stile = 0; stile < 4; ++stile) {
                short8 kf = *(const short8*)&Ks[(stile * 16 + l15) * 128 + ((ks * 4 + quad) ^ sw3) * 8];
                st[stile] = __builtin_amdgcn_mfma_f32_16x16x32_bf16(kf, qf[ks], st[stile], 0, 0, 0);
            }
        }
        __builtin_amdgcn_s_setprio(0);

        bool fullok = allseg1 && (s0 >= startb) && (s0 + 63 <= cur + t0) && (s0 + 63 < curT);

        // softmax: p = exp2(score*SCALE2); pack 4 s-consecutive f16 -> uint2 store
#pragma unroll
        for (int stile = 0; stile < 4; ++stile) {
            float p0, p1, p2, p3;
            if (fullok) {
                p0 = exp2f(st[stile][0] * SCALE2);
                p1 = exp2f(st[stile][1] * SCALE2);
                p2 = exp2f(st[stile][2] * SCALE2);
                p3 = exp2f(st[stile][3] * SCALE2);
            } else {
                float pp[4];
#pragma unroll
                for (int reg = 0; reg < 4; ++reg) {
                    int s = s0 + stile * 16 + quad * 4 + reg;
                    int kvseg = (s >= startb && s < curT) ? 1 : 0;
                    bool ok = (s <= ct) && (cls == kvseg);
                    pp[reg] = exp2f(ok ? st[stile][reg] * SCALE2 : -1e30f);
                }
                p0 = pp[0]; p1 = pp[1]; p2 = pp[2]; p3 = pp[3];
            }
            lsum += (p0 + p1) + (p2 + p3);
            H2U a, d;
            a.h = __builtin_amdgcn_cvt_pkrtz(p0, p1);
            d.h = __builtin_amdgcn_cvt_pkrtz(p2, p3);
            uint2 pk; pk.x = a.u; pk.y = d.u;
            // 16B slot = (stile*2 + (quad>>1)) ^ sw8 ; uint2 in half (quad&1)
            *(uint2*)&psrow[(((stile * 2 + (quad >> 1)) ^ sw8) << 3) + (quad & 1) * 4] = pk;
        }

        // O^T += V^T · P^T   (A = Vs f16, B = Ps f16) — own wave's Ps row only
        __builtin_amdgcn_s_setprio(1);
#pragma unroll
        for (int kk = 0; kk < 2; ++kk) {
            S8H8 pf;
            pf.s = *(const short8*)&psrow[((kk * 4 + quad) ^ sw8) << 3];
#pragma unroll
            for (int htile = 0; htile < 8; ++htile) {
                S8H8 vf;
                vf.s = *(const short8*)&Vs[(htile * 16 + l15) * 64 + ((kk * 4 + quad) ^ sw3) * 8];
                oT[htile] = __builtin_amdgcn_mfma_f32_16x16x32_f16(vf.h, pf.h, oT[htile], 0, 0, 0);
            }
        }
        __builtin_amdgcn_s_setprio(0);

        __syncthreads();   // WAR: next staging overwrites Ks/Vs
    }

    // l: sum across the 4 quads holding the same q (xor 16, 32)
    float l = lsum;
    l += __shfl_xor(l, 16);
    l += __shfl_xor(l, 32);
    float linv = (l > 0.f) ? (1.0f / l) : 0.f;

    // epilogue: O^T col=q(l15), row=h(quad*4+reg) -> packed bf16 stores
    {
        int trow = t0 + l15;
        size_t base = ((size_t)(b * Tc + trow) * Nc + n) * Hc;
#pragma unroll
        for (int htile = 0; htile < 8; ++htile) {
            float4v v = oT[htile];
            unsigned short r0 = f2bf(v[0] * linv);
            unsigned short r1 = f2bf(v[1] * linv);
            unsigned short r2 = f2bf(v[2] * linv);
            unsigned short r3 = f2bf(v[3] * linv);
            uint2 pk;
            pk.x = (unsigned)r0 | ((unsigned)r1 << 16);
            pk.y = (unsigned)r2 | ((unsigned)r3 << 16);
            *(uint2*)&Ob[base + htile * 16 + quad * 4] = pk;
        }
    }
}

// ---------------------------------------------------------------------------
extern "C" void kernel_launch(void* const* d_in, const int* in_sizes, int n_in,
                              void* d_out, int out_size, void* d_ws, size_t ws_size,
                              hipStream_t stream)
{
    const float* x        = (const float*)d_in[0];
    const float* q_w      = (const float*)d_in[1];
    const float* k_w      = (const float*)d_in[2];
    const float* v_w      = (const float*)d_in[3];
    const float* o_w      = (const float*)d_in[4];
    const float* q_norm_w = (const float*)d_in[5];
    const float* k_norm_w = (const float*)d_in[6];
    const float* k_cache  = (const float*)d_in[7];
    const float* v_cache  = (const float*)d_in[8];
    const int*   seg      = (const int*)d_in[9];
    const int*   startind = (const int*)d_in[10];
    const int*   cur_ptr  = (const int*)d_in[11];
    (void)in_sizes; (void)n_in; (void)out_size; (void)ws_size;

    char* base = (char*)d_ws;
    int* meta = (int*)base;                                          //      1024 B
    unsigned short* QKVh = (unsigned short*)(base + 1024);           // 33.55 MB [4096][4096]
    unsigned short* Kall = (unsigned short*)(base + 33555456);       //  8.39 MB bf16 [B][S][KH][H]
    unsigned short* Vt   = (unsigned short*)(base + 41944064);       //  8.39 MB f16  [B][KH][H][S]
    unsigned short* xb   = (unsigned short*)(base + 50332672);       // 16.78 MB; reused as Ob
    unsigned short* qkvwT= (unsigned short*)(base + 67109888);       // 16.78 MB [4096][2048]
    unsigned short* owT  = (unsigned short*)(base + 83887104);       //  8.39 MB [2048][2048]
    unsigned short* Ob   = xb;

    // 1) fused prep: meta + cast + 4 transposes
    prep<<<Bc + 4096 + 4096 + 2048 + 2048 + 4096, 256, 0, stream>>>(
        x, q_w, k_w, v_w, o_w, seg, startind, meta, xb, qkvwT, owT);

    // 2) fused QKV projection: [4096 x 2048] @ [2048 x 4096] (2-barrier 256^2)
    gemm256<<<dim3(16, 16), 512, 0, stream>>>(xb, qkvwT, QKVh, Bc * Tc, 4096, Dc, 0);

    // 3) fused post: norm+rope, K-cache fill, V transpose (f16)
    post<<<24576 + 2048 + 2048, 256, 0, stream>>>(QKVh, Kall, Vt,
        q_norm_w, k_norm_w, seg, meta, cur_ptr, k_cache, v_cache);

    // 4) flash attention: 128-row tiles, 8-wave blocks (2 waves/SIMD min)
    flash_mfma<<<Bc * Nc * (Tc / 128), 512, 0, stream>>>(QKVh, Kall, Vt, seg, meta, cur_ptr, Ob);

    // 5) O projection -> fp32 out (2-barrier 256^2)
    gemm256<<<dim3(8, 16), 512, 0, stream>>>(Ob, owT, d_out, Bc * Tc, Dc, Nc * Hc, 1);
}

// Round 7
// 380.907 us; speedup vs baseline: 1.2017x; 1.0325x over previous
//
#include <hip/hip_runtime.h>
#include <hip/hip_fp16.h>
#include <climits>
#include <math.h>

#define Bc   2
#define Tc   2048
#define Dc   2048
#define Nc   16
#define KHc  8
#define Hc   128
#define Sc   2048

constexpr float EPSc   = 1e-6f;
constexpr float SCALE2 = 0.1275174477984469f;     // (1/sqrt(128)) * log2(e)

typedef short short8 __attribute__((ext_vector_type(8)));
typedef _Float16 half8 __attribute__((ext_vector_type(8)));
typedef __fp16 fp16x2 __attribute__((ext_vector_type(2)));
typedef float float4v __attribute__((ext_vector_type(4)));

union U16x8 { uint4 u; short8 s8; half8 h8; unsigned short us[8]; };
union H2U  { fp16x2 h; unsigned u; };
union S8H8 { short8 s; half8 h; };

__device__ __forceinline__ unsigned short f2bf(float f) {
    union { float f; unsigned u; } v; v.f = f;
    unsigned r = v.u + 0x7FFFu + ((v.u >> 16) & 1u);
    return (unsigned short)(r >> 16);
}
__device__ __forceinline__ float bf2f(unsigned short u) {
    union { unsigned u; float f; } v; v.u = ((unsigned)u) << 16;
    return v.f;
}

// ---------------------------------------------------------------------------
// prep: fused meta + x-cast + 4 weight transposes (12 launches -> 1)
// ---------------------------------------------------------------------------
__device__ __forceinline__ void tc_body(const float* __restrict__ in,
                                        unsigned short* __restrict__ out,
                                        int R, int C, int bx, int by, int tid,
                                        float tile[32][33])
{
    int c0 = bx * 32, r0 = by * 32;
#pragma unroll
    for (int i = 0; i < 4; ++i) {
        int row = (tid >> 5) + i * 8, col = tid & 31;
        tile[row][col] = in[(size_t)(r0 + row) * C + c0 + col];
    }
    __syncthreads();
#pragma unroll
    for (int i = 0; i < 4; ++i) {
        int rowo = (tid >> 5) + i * 8, colo = tid & 31;
        out[(size_t)(c0 + rowo) * R + r0 + colo] = f2bf(tile[colo][rowo]);
    }
}

__global__ __launch_bounds__(256) void prep(const float* __restrict__ x,
                                            const float* __restrict__ qw,
                                            const float* __restrict__ kw,
                                            const float* __restrict__ vw,
                                            const float* __restrict__ ow,
                                            const int* __restrict__ seg,
                                            const int* __restrict__ start_ind,
                                            int* __restrict__ meta,
                                            unsigned short* __restrict__ xb,
                                            unsigned short* __restrict__ qkvwT,
                                            unsigned short* __restrict__ owT)
{
    __shared__ float tile[32][33];
    __shared__ int s_max, s_amax, s_nz;
    int id = blockIdx.x;
    int tid = threadIdx.x;

    if (id < Bc) {   // meta
        int b = id;
        if (tid == 0) { s_max = INT_MIN; s_amax = Tc; s_nz = Tc; }
        __syncthreads();
        int lmax = INT_MIN;
        for (int t = tid; t < Tc; t += 256) lmax = max(lmax, seg[b * Tc + t]);
        atomicMax(&s_max, lmax);
        __syncthreads();
        int mv = s_max;
        int lamax = Tc, lnz = Tc;
        for (int t = tid; t < Tc; t += 256) {
            int v = seg[b * Tc + t];
            if (v == mv) lamax = min(lamax, t);
            if (v != 0)  lnz   = min(lnz, t);
        }
        atomicMin(&s_amax, lamax);
        atomicMin(&s_nz, lnz);
        __syncthreads();
        if (tid == 0) {
            meta[b] = s_amax;
            int st = start_ind[b];
            meta[Bc + b] = (st < 0) ? s_nz : st;
        }
        return;
    }
    id -= Bc;
    if (id < 4096) {   // cast x
        size_t base = ((size_t)id * 256 + tid) * 8;
        float4 a = *(const float4*)&x[base];
        float4 b = *(const float4*)&x[base + 4];
        U16x8 o;
        o.us[0] = f2bf(a.x); o.us[1] = f2bf(a.y); o.us[2] = f2bf(a.z); o.us[3] = f2bf(a.w);
        o.us[4] = f2bf(b.x); o.us[5] = f2bf(b.y); o.us[6] = f2bf(b.z); o.us[7] = f2bf(b.w);
        *(uint4*)&xb[base] = o.u;
        return;
    }
    id -= 4096;
    if (id < 4096) { tc_body(qw, qkvwT, 2048, 2048, id & 63, id >> 6, tid, tile); return; }
    id -= 4096;
    if (id < 2048) { tc_body(kw, qkvwT + (size_t)2048 * 2048, 2048, 1024, id & 31, id >> 5, tid, tile); return; }
    id -= 2048;
    if (id < 2048) { tc_body(vw, qkvwT + (size_t)3072 * 2048, 2048, 1024, id & 31, id >> 5, tid, tile); return; }
    id -= 2048;
    tc_body(ow, owT, 2048, 2048, id & 63, id >> 6, tid, tile);
}

// ---------------------------------------------------------------------------
// 128x128 bf16 MFMA GEMM (R7): C[M,N] = A[M,K] * BT[N,K]^T.
//   256 thr = 4 waves (2M x 2N), BK=64, double-buffered LDS = 64 KB
//   -> 2 blocks/CU resident. Rationale (R4/R5/R6 post-mortems): every
//   1-block/CU 256^2 schedule lands at ~35% MfmaUtil because all sync
//   waits expose on the whole CU; a second independent block cross-hides
//   them (the R3 flash win / m114 mechanism).
//   Per K-tile: chunk1 {stage B(kt+1)->buf^1; read all 16 frags; 16 MFMA
//   (ni 0,1); lgkmcnt(0); barrier} chunk2 {stage A(kt+2)->buf; 16 MFMA
//   (ni 2,3); vmcnt(4); barrier}. Counted vmcnt ledger: steady-state 12
//   in flight at tile end, oldest 8 = next tile's A+B landed, A(kt+2)
//   stays flying; vmcnt(0) only in the tail. Stage/read swizzle pair
//   identical to R6 (harness-verified): source col-slot pre-XORed by
//   row&7, read slot = (kk*4+quad) ^ (l15&7).
//   Accumulation order per C element: kk0,kk1 per kt, kt ascending.
// ---------------------------------------------------------------------------
__global__ __launch_bounds__(256, 2) void gemm128(const unsigned short* __restrict__ A,
                                                  const unsigned short* __restrict__ BT,
                                                  void* __restrict__ Cout,
                                                  int M, int N, int K, int out_fp32)
{
    __shared__ __align__(16) unsigned short As[2 * 8192];   // 32 KB
    __shared__ __align__(16) unsigned short Bs[2 * 8192];   // 32 KB

    int tid = threadIdx.x;
    int lane = tid & 63, w = tid >> 6;            // w in 0..3
    int quad = lane >> 4, l15 = lane & 15;

    // bijective XCD swizzle on linear block id (nwg % 8 == 0 for our shapes)
    int gx = gridDim.x;
    int nwg = gx * gridDim.y;
    int lin = blockIdx.y * gx + blockIdx.x;
    int swz = (lin & 7) * (nwg >> 3) + (lin >> 3);
    int bm = (swz / gx) * 128, bn = (swz % gx) * 128;

    int KT = K >> 6;

    // ---- staging source (pre-swizzled column so LDS dest stays linear)
    int colswz = (((lane & 7) ^ ((lane >> 3) & 7)) << 3);
    int r0 = w * 32 + (lane >> 3);                // wave w covers rows [w*32, w*32+32)
    const unsigned short* Ab = A + (size_t)(bm + r0) * K + colswz;
    const unsigned short* Bb = BT + (size_t)(bn + r0) * K + colswz;
    size_t rowK8 = (size_t)8 * K;                 // +8 rows per staging step

    unsigned short* dA = As + w * 2048;           // + bufp*8192 + i*512
    unsigned short* dB = Bs + w * 2048;

    auto stA = [&](int kt, int bufp) __attribute__((always_inline)) {
#pragma unroll
        for (int i = 0; i < 4; ++i)
            __builtin_amdgcn_global_load_lds(
                (__attribute__((address_space(1))) void*)(Ab + (size_t)i * rowK8 + (size_t)kt * 64),
                (__attribute__((address_space(3))) void*)(dA + bufp * 8192 + i * 512), 16, 0, 0);
    };
    auto stB = [&](int kt, int bufp) __attribute__((always_inline)) {
#pragma unroll
        for (int i = 0; i < 4; ++i)
            __builtin_amdgcn_global_load_lds(
                (__attribute__((address_space(1))) void*)(Bb + (size_t)i * rowK8 + (size_t)kt * 64),
                (__attribute__((address_space(3))) void*)(dB + bufp * 8192 + i * 512), 16, 0, 0);
    };

    // ---- fragment read bases (swizzled read: slot ^= row&7, row&7 == l15&7)
    int wm = (w >> 1) * 64, wn = (w & 1) * 64;
    int swk = l15 & 7;
    int cof0 = ((quad) ^ swk) << 3;               // kk=0 logical col quad*8
    int cof1 = ((4 + quad) ^ swk) << 3;           // kk=1
    const int arow = (wm + l15) * 64;
    const int brow = (wn + l15) * 64;

    float4v acc[4][4];
#pragma unroll
    for (int i = 0; i < 4; ++i)
#pragma unroll
        for (int j = 0; j < 4; ++j) acc[i][j] = (float4v)0.f;

    // ---- prologue: tile0 -> buf0 (8 loads), A(1) -> buf1 (4 loads)
    stA(0, 0); stB(0, 0);
    stA(1, 1);
    asm volatile("s_waitcnt vmcnt(4)" ::: "memory");   // tile 0 fully landed
    __builtin_amdgcn_s_barrier();
    asm volatile("" ::: "memory");

    auto ktile = [&](int kt, int bufp) __attribute__((always_inline)) {
        const unsigned short* ab = As + bufp * 8192 + arow;
        const unsigned short* bb = Bs + bufp * 8192 + brow;
        short8 af[2][4], bf[2][4];

        // ---- chunk1: stage B(kt+1)->buf p^1; read all 16 frags; 16 MFMA
        if (kt + 1 < KT) stB(kt + 1, bufp ^ 1);
#pragma unroll
        for (int mi = 0; mi < 4; ++mi) {
            af[0][mi] = *(const short8*)&ab[mi * 1024 + cof0];
            af[1][mi] = *(const short8*)&ab[mi * 1024 + cof1];
        }
#pragma unroll
        for (int ni = 0; ni < 4; ++ni) {
            bf[0][ni] = *(const short8*)&bb[ni * 1024 + cof0];
            bf[1][ni] = *(const short8*)&bb[ni * 1024 + cof1];
        }
        __builtin_amdgcn_s_setprio(1);
#pragma unroll
        for (int kk = 0; kk < 2; ++kk)
#pragma unroll
            for (int mi = 0; mi < 4; ++mi)
#pragma unroll
                for (int ni = 0; ni < 2; ++ni)
                    acc[mi][ni] = __builtin_amdgcn_mfma_f32_16x16x32_bf16(af[kk][mi], bf[kk][ni], acc[mi][ni], 0, 0, 0);
        __builtin_amdgcn_s_setprio(0);
        // hazard 1: all LDS reads of buf p in regs before A-stage overwrites
        asm volatile("s_waitcnt lgkmcnt(0)" ::: "memory");
        __builtin_amdgcn_sched_barrier(0);
        __builtin_amdgcn_s_barrier();
        asm volatile("" ::: "memory");

        // ---- chunk2: stage A(kt+2)->buf p; 16 MFMA (ni 2,3)
        bool sA = (kt + 2) < KT;
        if (sA) stA(kt + 2, bufp);
        __builtin_amdgcn_s_setprio(1);
#pragma unroll
        for (int kk = 0; kk < 2; ++kk)
#pragma unroll
            for (int mi = 0; mi < 4; ++mi)
#pragma unroll
                for (int ni = 2; ni < 4; ++ni)
                    acc[mi][ni] = __builtin_amdgcn_mfma_f32_16x16x32_bf16(af[kk][mi], bf[kk][ni], acc[mi][ni], 0, 0, 0);
        __builtin_amdgcn_s_setprio(0);
        // hazard 2: next tile's A+B (oldest 8 of <=12 outstanding) landed
        if (sA) asm volatile("s_waitcnt vmcnt(4)" ::: "memory");
        else    asm volatile("s_waitcnt vmcnt(0)" ::: "memory");
        __builtin_amdgcn_sched_barrier(0);
        __builtin_amdgcn_s_barrier();
        asm volatile("" ::: "memory");
    };

    for (int kt = 0; kt < KT; kt += 2) {
        ktile(kt, 0);
        ktile(kt + 1, 1);
    }

    // ---- epilogue: per-wave 64x64 tile, C row = quad*4+reg, col = l15
#pragma unroll
    for (int mi = 0; mi < 4; ++mi)
#pragma unroll
        for (int ni = 0; ni < 4; ++ni)
#pragma unroll
            for (int reg = 0; reg < 4; ++reg) {
                int row = bm + wm + mi * 16 + quad * 4 + reg;
                int col = bn + wn + ni * 16 + l15;
                float v = acc[mi][ni][reg];
                if (out_fp32) ((float*)Cout)[(size_t)row * N + col] = v;
                else ((unsigned short*)Cout)[(size_t)row * N + col] = f2bf(v);
            }
}

// ---------------------------------------------------------------------------
// post: fused norm_rope (Q in-place, K -> Kall) + K-cache fill + V transpose
// ---------------------------------------------------------------------------
__global__ __launch_bounds__(256) void post(unsigned short* __restrict__ QKVh,
                                            unsigned short* __restrict__ Kall,
                                            unsigned short* __restrict__ Vt,
                                            const float* __restrict__ qw,
                                            const float* __restrict__ kw,
                                            const int* __restrict__ seg,
                                            const int* __restrict__ meta,
                                            const int* __restrict__ cur_ptr,
                                            const float* __restrict__ kc,
                                            const float* __restrict__ vc)
{
    int id = blockIdx.x;
    int tid = threadIdx.x;
    int cur = cur_ptr[0];

    if (id < 24576) {   // norm + rope
        int rowid = id * 4 + (tid >> 6);
        int lane = tid & 63;
        int hh = rowid % 24;
        int bt = rowid / 24;
        int t = bt & (Tc - 1);
        int b = bt >> 11;

        const unsigned short* in;
        unsigned short* out;
        const float* wt;
        if (hh < 16) {
            unsigned short* p = QKVh + (size_t)bt * 4096 + hh * Hc;
            in = p; out = p; wt = qw;
        } else {
            int kh = hh - 16;
            in = QKVh + (size_t)bt * 4096 + 2048 + kh * Hc;
            out = Kall + (((size_t)b * Sc + cur + t) * KHc + kh) * Hc;
            wt = kw;
        }
        float v1 = bf2f(in[lane]), v2 = bf2f(in[lane + 64]);
        float ssq = v1 * v1 + v2 * v2;
#pragma unroll
        for (int off = 1; off < 64; off <<= 1) ssq += __shfl_xor(ssq, off);
        float rinv = rsqrtf(ssq * (1.0f / Hc) + EPSc);

        int sg = seg[bt];
        long long pos = (sg != 0) ? (long long)(t - meta[b]) : (long long)(1 << 30);
        float posf = (float)(pos + (long long)cur);
        float inv_freq = exp2f(-(float)lane * (19.931568569324174f / 64.0f));
        float s, c;
        sincosf(posf * inv_freq, &s, &c);

        float n1 = wt[lane] * v1 * rinv;
        float n2 = wt[lane + 64] * v2 * rinv;
        out[lane]      = f2bf(n1 * c - n2 * s);
        out[lane + 64] = f2bf(n2 * c + n1 * s);
        return;
    }
    id -= 24576;
    if (id < 2048) {   // K cache fill
        size_t base = ((size_t)id * 256 + tid) * 8;
        int s = (int)((base >> 10) & (Sc - 1));
        if (s >= cur && s < cur + Tc) return;
        float4 a = *(const float4*)&kc[base];
        float4 b = *(const float4*)&kc[base + 4];
        U16x8 o;
        o.us[0] = f2bf(a.x); o.us[1] = f2bf(a.y); o.us[2] = f2bf(a.z); o.us[3] = f2bf(a.w);
        o.us[4] = f2bf(b.x); o.us[5] = f2bf(b.y); o.us[6] = f2bf(b.z); o.us[7] = f2bf(b.w);
        *(uint4*)&Kall[base] = o.u;
        return;
    }
    id -= 2048;
    {   // V transpose -> f16
        int gid = id * 256 + tid;
        int h  = gid & 127;
        int s8 = ((gid >> 7) & 255) * 8;
        int kh = (gid >> 15) & 7;
        int b  = gid >> 18;
        int curT = cur + Tc;
        unsigned short tmp[8];
#pragma unroll
        for (int e = 0; e < 8; ++e) {
            int s = s8 + e;
            float f;
            if (s >= cur && s < curT)
                f = bf2f(QKVh[(size_t)(b * Tc + (s - cur)) * 4096 + 3072 + kh * Hc + h]);
            else
                f = vc[((size_t)(b * Sc + s) * KHc + kh) * Hc + h];
            tmp[e] = __half_as_ushort(__float2half(f));
        }
        *(uint4*)&Vt[(((size_t)b * KHc + kh) * Hc + h) * Sc + s8] = *(uint4*)tmp;
    }
}

// ---------------------------------------------------------------------------
// MFMA flash attention, S^T formulation — 8-wave version (R3, proven):
//   128-row q-tiles, 512-thread blocks, each wave owns 16 q-rows.
//   LDS = Ks 16K + Vs 16K + Ps 16K = 48 KB.
// ---------------------------------------------------------------------------
__global__ __launch_bounds__(512, 4) void flash_mfma(const unsigned short* __restrict__ Qb,
                                                     const unsigned short* __restrict__ Kall,
                                                     const unsigned short* __restrict__ Vt,
                                                     const int* __restrict__ seg,
                                                     const int* __restrict__ meta,
                                                     const int* __restrict__ cur_ptr,
                                                     unsigned short* __restrict__ Ob)
{
    __shared__ __align__(16) unsigned short Ks[64 * 128];   // bf16 [s][h], swizzled
    __shared__ __align__(16) unsigned short Vs[128 * 64];   // f16  [h][s], swizzled
    __shared__ __align__(16) unsigned short Ps[128 * 64];   // f16  [q][s], XOR-swizzled

    int tid = threadIdx.x;
    int lane = tid & 63, w = tid >> 6;          // w in 0..7
    int quad = lane >> 4, l15 = lane & 15;
    int bid = blockIdx.x;
    int raw = bid & 15;
    int n  = (bid >> 4) & 15;
    int b  = bid >> 8;
    int qt = (b == 0) ? raw : (15 - raw);
    int kh = n >> 1;
    int cur = cur_ptr[0];
    int startb = meta[Bc + b];
    int curT = cur + Tc;
    int t0 = qt * 128 + w * 16;                 // this wave's 16 q-rows

    // Q fragments (B-operand layout == A layout: l15 -> q, quad*8+j -> h)
    short8 qf[4];
#pragma unroll
    for (int ks = 0; ks < 4; ++ks) {
        int row = t0 + l15;
        U16x8 uq;
        uq.u = *(const uint4*)&Qb[(size_t)(b * Tc + row) * 4096 + n * Hc + ks * 32 + quad * 8];
        qf[ks] = uq.s8;
    }

    // per-lane mask metadata (q = l15-indexed)
    int trow0 = t0 + l15;
    int sg0 = seg[b * Tc + trow0];
    int cls = (sg0 == 0) ? 0 : ((sg0 == 1) ? 1 : 2);
    int ct  = cur + trow0;
    unsigned long long mball = __ballot(cls == 1);
    bool allseg1 = (mball == 0xFFFFFFFFFFFFFFFFull);

    float lsum = 0.f;
    float4v oT[8];   // [htile]
#pragma unroll
    for (int i = 0; i < 8; ++i) oT[i] = (float4v)0.f;

    int s_end = min(Sc, cur + qt * 128 + 128);
    int nch = (s_end + 63) >> 6;

    // staging geometry (per wave: 2 K + 2 V global_load_lds per chunk)
    const size_t kstride = (size_t)KHc * Hc;
    const unsigned short* kptr[2];
    unsigned short* kdst[2];
#pragma unroll
    for (int i = 0; i < 2; ++i) {
        int j = w * 2 + i;                      // 0..15
        int row = j * 4 + (lane >> 4);          // 0..63
        int pl = lane & 15;
        int pg = pl ^ ((row >> 1) & 7);
        kptr[i] = Kall + (size_t)b * Sc * kstride + (size_t)row * kstride + kh * Hc + pg * 8;
        kdst[i] = Ks + j * 512;
    }
    const unsigned short* vptr[2];
    unsigned short* vdst[2];
#pragma unroll
    for (int i = 0; i < 2; ++i) {
        int j = w * 2 + i;                      // 0..15
        int h = j * 8 + (lane >> 3);            // 0..127
        int pl = lane & 7;
        int pg = pl ^ ((h >> 1) & 7);
        vptr[i] = Vt + ((size_t)b * KHc + kh) * (size_t)Hc * Sc + (size_t)h * Sc + pg * 8;
        vdst[i] = Vs + j * 512;
    }
    int sw3 = (l15 >> 1) & 7;
    int sw8 = l15 & 7;                          // Ps 16B-slot swizzle key (== row&7)
    unsigned short* psrow = Ps + (w * 16 + l15) * 64;   // this wave's q-row

    for (int c = 0; c < nch; ++c) {
        int s0 = c * 64;
#pragma unroll
        for (int i = 0; i < 2; ++i) {
            __builtin_amdgcn_global_load_lds(
                (__attribute__((address_space(1))) void*)(kptr[i] + (size_t)s0 * kstride),
                (__attribute__((address_space(3))) void*)kdst[i], 16, 0, 0);
            __builtin_amdgcn_global_load_lds(
                (__attribute__((address_space(1))) void*)(vptr[i] + s0),
                (__attribute__((address_space(3))) void*)vdst[i], 16, 0, 0);
        }
        __syncthreads();

        // S^T = K·Q^T : st[stile], row=s, col=q
        float4v st[4];
#pragma unroll
        for (int i = 0; i < 4; ++i) st[i] = (float4v)0.f;
        __builtin_amdgcn_s_setprio(1);
#pragma unroll
        for (int ks = 0; ks < 4; ++ks) {
#pragma unroll
            for (int stile = 0; stile < 4; ++stile) {
                short8 kf = *(const short8*)&Ks[(stile * 16 + l15) * 128 + ((ks * 4 + quad) ^ sw3) * 8];
                st[stile] = __builtin_amdgcn_mfma_f32_16x16x32_bf16(kf, qf[ks], st[stile], 0, 0, 0);
            }
        }
        __builtin_amdgcn_s_setprio(0);

        bool fullok = allseg1 && (s0 >= startb) && (s0 + 63 <= cur + t0) && (s0 + 63 < curT);

        // softmax: p = exp2(score*SCALE2); pack 4 s-consecutive f16 -> uint2 store
#pragma unroll
        for (int stile = 0; stile < 4; ++stile) {
            float p0, p1, p2, p3;
            if (fullok) {
                p0 = exp2f(st[stile][0] * SCALE2);
                p1 = exp2f(st[stile][1] * SCALE2);
                p2 = exp2f(st[stile][2] * SCALE2);
                p3 = exp2f(st[stile][3] * SCALE2);
            } else {
                float pp[4];
#pragma unroll
                for (int reg = 0; reg < 4; ++reg) {
                    int s = s0 + stile * 16 + quad * 4 + reg;
                    int kvseg = (s >= startb && s < curT) ? 1 : 0;
                    bool ok = (s <= ct) && (cls == kvseg);
                    pp[reg] = exp2f(ok ? st[stile][reg] * SCALE2 : -1e30f);
                }
                p0 = pp[0]; p1 = pp[1]; p2 = pp[2]; p3 = pp[3];
            }
            lsum += (p0 + p1) + (p2 + p3);
            H2U a, d;
            a.h = __builtin_amdgcn_cvt_pkrtz(p0, p1);
            d.h = __builtin_amdgcn_cvt_pkrtz(p2, p3);
            uint2 pk; pk.x = a.u; pk.y = d.u;
            // 16B slot = (stile*2 + (quad>>1)) ^ sw8 ; uint2 in half (quad&1)
            *(uint2*)&psrow[(((stile * 2 + (quad >> 1)) ^ sw8) << 3) + (quad & 1) * 4] = pk;
        }

        // O^T += V^T · P^T   (A = Vs f16, B = Ps f16) — own wave's Ps row only
        __builtin_amdgcn_s_setprio(1);
#pragma unroll
        for (int kk = 0; kk < 2; ++kk) {
            S8H8 pf;
            pf.s = *(const short8*)&psrow[((kk * 4 + quad) ^ sw8) << 3];
#pragma unroll
            for (int htile = 0; htile < 8; ++htile) {
                S8H8 vf;
                vf.s = *(const short8*)&Vs[(htile * 16 + l15) * 64 + ((kk * 4 + quad) ^ sw3) * 8];
                oT[htile] = __builtin_amdgcn_mfma_f32_16x16x32_f16(vf.h, pf.h, oT[htile], 0, 0, 0);
            }
        }
        __builtin_amdgcn_s_setprio(0);

        __syncthreads();   // WAR: next staging overwrites Ks/Vs
    }

    // l: sum across the 4 quads holding the same q (xor 16, 32)
    float l = lsum;
    l += __shfl_xor(l, 16);
    l += __shfl_xor(l, 32);
    float linv = (l > 0.f) ? (1.0f / l) : 0.f;

    // epilogue: O^T col=q(l15), row=h(quad*4+reg) -> packed bf16 stores
    {
        int trow = t0 + l15;
        size_t base = ((size_t)(b * Tc + trow) * Nc + n) * Hc;
#pragma unroll
        for (int htile = 0; htile < 8; ++htile) {
            float4v v = oT[htile];
            unsigned short r0 = f2bf(v[0] * linv);
            unsigned short r1 = f2bf(v[1] * linv);
            unsigned short r2 = f2bf(v[2] * linv);
            unsigned short r3 = f2bf(v[3] * linv);
            uint2 pk;
            pk.x = (unsigned)r0 | ((unsigned)r1 << 16);
            pk.y = (unsigned)r2 | ((unsigned)r3 << 16);
            *(uint2*)&Ob[base + htile * 16 + quad * 4] = pk;
        }
    }
}

// ---------------------------------------------------------------------------
extern "C" void kernel_launch(void* const* d_in, const int* in_sizes, int n_in,
                              void* d_out, int out_size, void* d_ws, size_t ws_size,
                              hipStream_t stream)
{
    const float* x        = (const float*)d_in[0];
    const float* q_w      = (const float*)d_in[1];
    const float* k_w      = (const float*)d_in[2];
    const float* v_w      = (const float*)d_in[3];
    const float* o_w      = (const float*)d_in[4];
    const float* q_norm_w = (const float*)d_in[5];
    const float* k_norm_w = (const float*)d_in[6];
    const float* k_cache  = (const float*)d_in[7];
    const float* v_cache  = (const float*)d_in[8];
    const int*   seg      = (const int*)d_in[9];
    const int*   startind = (const int*)d_in[10];
    const int*   cur_ptr  = (const int*)d_in[11];
    (void)in_sizes; (void)n_in; (void)out_size; (void)ws_size;

    char* base = (char*)d_ws;
    int* meta = (int*)base;                                          //      1024 B
    unsigned short* QKVh = (unsigned short*)(base + 1024);           // 33.55 MB [4096][4096]
    unsigned short* Kall = (unsigned short*)(base + 33555456);       //  8.39 MB bf16 [B][S][KH][H]
    unsigned short* Vt   = (unsigned short*)(base + 41944064);       //  8.39 MB f16  [B][KH][H][S]
    unsigned short* xb   = (unsigned short*)(base + 50332672);       // 16.78 MB; reused as Ob
    unsigned short* qkvwT= (unsigned short*)(base + 67109888);       // 16.78 MB [4096][2048]
    unsigned short* owT  = (unsigned short*)(base + 83887104);       //  8.39 MB [2048][2048]
    unsigned short* Ob   = xb;

    // 1) fused prep: meta + cast + 4 transposes
    prep<<<Bc + 4096 + 4096 + 2048 + 2048 + 4096, 256, 0, stream>>>(
        x, q_w, k_w, v_w, o_w, seg, startind, meta, xb, qkvwT, owT);

    // 2) fused QKV projection: [4096 x 2048] @ [2048 x 4096] (128^2, 2 blk/CU)
    gemm128<<<dim3(32, 32), 256, 0, stream>>>(xb, qkvwT, QKVh, Bc * Tc, 4096, Dc, 0);

    // 3) fused post: norm+rope, K-cache fill, V transpose (f16)
    post<<<24576 + 2048 + 2048, 256, 0, stream>>>(QKVh, Kall, Vt,
        q_norm_w, k_norm_w, seg, meta, cur_ptr, k_cache, v_cache);

    // 4) flash attention: 128-row tiles, 8-wave blocks (2 waves/SIMD min)
    flash_mfma<<<Bc * Nc * (Tc / 128), 512, 0, stream>>>(QKVh, Kall, Vt, seg, meta, cur_ptr, Ob);

    // 5) O projection -> fp32 out (128^2, full-chip grid 512 = 2 blk/CU)
    gemm128<<<dim3(16, 32), 256, 0, stream>>>(Ob, owT, d_out, Bc * Tc, Dc, Nc * Hc, 1);
}

// Round 8
// 369.255 us; speedup vs baseline: 1.2397x; 1.0316x over previous
//
#include <hip/hip_runtime.h>
#include <hip/hip_fp16.h>
#include <climits>
#include <math.h>

#define Bc   2
#define Tc   2048
#define Dc   2048
#define Nc   16
#define KHc  8
#define Hc   128
#define Sc   2048

constexpr float EPSc   = 1e-6f;
constexpr float SCALE2 = 0.1275174477984469f;     // (1/sqrt(128)) * log2(e)

typedef short short8 __attribute__((ext_vector_type(8)));
typedef _Float16 half8 __attribute__((ext_vector_type(8)));
typedef __fp16 fp16x2 __attribute__((ext_vector_type(2)));
typedef float float4v __attribute__((ext_vector_type(4)));

union U16x8 { uint4 u; short8 s8; half8 h8; unsigned short us[8]; };
union H2U  { fp16x2 h; unsigned u; };
union S8H8 { short8 s; half8 h; };

__device__ __forceinline__ unsigned short f2bf(float f) {
    union { float f; unsigned u; } v; v.f = f;
    unsigned r = v.u + 0x7FFFu + ((v.u >> 16) & 1u);
    return (unsigned short)(r >> 16);
}
__device__ __forceinline__ float bf2f(unsigned short u) {
    union { unsigned u; float f; } v; v.u = ((unsigned)u) << 16;
    return v.f;
}

// ---------------------------------------------------------------------------
// prep: fused meta + x-cast + 4 weight transposes.
// R8: transpose writes vectorized (G13) — each thread packs 8 bf16 -> uint4
// (was 4 scalar ushort stores/thread).
// ---------------------------------------------------------------------------
__device__ __forceinline__ void tc_body(const float* __restrict__ in,
                                        unsigned short* __restrict__ out,
                                        int R, int C, int bx, int by, int tid,
                                        float tile[32][33])
{
    int c0 = bx * 32, r0 = by * 32;
    {   // read: 32 rows x 32 cols, float4 per thread (fully coalesced)
        int row = tid >> 3, col = (tid & 7) * 4;
        float4 v = *(const float4*)&in[(size_t)(r0 + row) * C + c0 + col];
        tile[row][col]     = v.x;
        tile[row][col + 1] = v.y;
        tile[row][col + 2] = v.z;
        tile[row][col + 3] = v.w;
    }
    __syncthreads();
    if (tid < 128) {   // write: out-row = c0+rowo, 8 bf16 per thread -> uint4
        int rowo = tid >> 2, s8 = (tid & 3) * 8;
        U16x8 o;
#pragma unroll
        for (int k = 0; k < 8; ++k) o.us[k] = f2bf(tile[s8 + k][rowo]);
        *(uint4*)&out[(size_t)(c0 + rowo) * R + r0 + s8] = o.u;
    }
}

__global__ __launch_bounds__(256) void prep(const float* __restrict__ x,
                                            const float* __restrict__ qw,
                                            const float* __restrict__ kw,
                                            const float* __restrict__ vw,
                                            const float* __restrict__ ow,
                                            const int* __restrict__ seg,
                                            const int* __restrict__ start_ind,
                                            int* __restrict__ meta,
                                            unsigned short* __restrict__ xb,
                                            unsigned short* __restrict__ qkvwT,
                                            unsigned short* __restrict__ owT)
{
    __shared__ float tile[32][33];
    __shared__ int s_max, s_amax, s_nz;
    int id = blockIdx.x;
    int tid = threadIdx.x;

    if (id < Bc) {   // meta
        int b = id;
        if (tid == 0) { s_max = INT_MIN; s_amax = Tc; s_nz = Tc; }
        __syncthreads();
        int lmax = INT_MIN;
        for (int t = tid; t < Tc; t += 256) lmax = max(lmax, seg[b * Tc + t]);
        atomicMax(&s_max, lmax);
        __syncthreads();
        int mv = s_max;
        int lamax = Tc, lnz = Tc;
        for (int t = tid; t < Tc; t += 256) {
            int v = seg[b * Tc + t];
            if (v == mv) lamax = min(lamax, t);
            if (v != 0)  lnz   = min(lnz, t);
        }
        atomicMin(&s_amax, lamax);
        atomicMin(&s_nz, lnz);
        __syncthreads();
        if (tid == 0) {
            meta[b] = s_amax;
            int st = start_ind[b];
            meta[Bc + b] = (st < 0) ? s_nz : st;
        }
        return;
    }
    id -= Bc;
    if (id < 4096) {   // cast x
        size_t base = ((size_t)id * 256 + tid) * 8;
        float4 a = *(const float4*)&x[base];
        float4 b = *(const float4*)&x[base + 4];
        U16x8 o;
        o.us[0] = f2bf(a.x); o.us[1] = f2bf(a.y); o.us[2] = f2bf(a.z); o.us[3] = f2bf(a.w);
        o.us[4] = f2bf(b.x); o.us[5] = f2bf(b.y); o.us[6] = f2bf(b.z); o.us[7] = f2bf(b.w);
        *(uint4*)&xb[base] = o.u;
        return;
    }
    id -= 4096;
    if (id < 4096) { tc_body(qw, qkvwT, 2048, 2048, id & 63, id >> 6, tid, tile); return; }
    id -= 4096;
    if (id < 2048) { tc_body(kw, qkvwT + (size_t)2048 * 2048, 2048, 1024, id & 31, id >> 5, tid, tile); return; }
    id -= 2048;
    if (id < 2048) { tc_body(vw, qkvwT + (size_t)3072 * 2048, 2048, 1024, id & 31, id >> 5, tid, tile); return; }
    id -= 2048;
    tc_body(ow, owT, 2048, 2048, id & 63, id >> 6, tid, tile);
}

// ---------------------------------------------------------------------------
// 256x256 8-phase bf16 MFMA GEMM (R4 form — best measured QKV: 78.9 us).
// ---------------------------------------------------------------------------
#define GSYNC_IN()  do { asm volatile("" ::: "memory"); \
                         __builtin_amdgcn_s_barrier(); \
                         asm volatile("s_waitcnt lgkmcnt(0)" ::: "memory"); \
                         __builtin_amdgcn_sched_barrier(0); \
                         __builtin_amdgcn_s_setprio(1); } while (0)
#define GSYNC_OUT() do { __builtin_amdgcn_s_setprio(0); \
                         __builtin_amdgcn_sched_barrier(0); \
                         asm volatile("" ::: "memory"); \
                         __builtin_amdgcn_s_barrier(); } while (0)
#define GSYNC_OUT_KT() do { __builtin_amdgcn_s_setprio(0); \
                         __builtin_amdgcn_sched_barrier(0); \
                         asm volatile("s_waitcnt vmcnt(4)" ::: "memory"); \
                         __builtin_amdgcn_s_barrier(); \
                         asm volatile("" ::: "memory"); } while (0)

__global__ __launch_bounds__(512, 2) void gemm256(const unsigned short* __restrict__ A,
                                                  const unsigned short* __restrict__ BT,
                                                  void* __restrict__ Cout,
                                                  int M, int N, int K, int out_fp32)
{
    __shared__ __align__(16) unsigned short As[2 * 16384];   // 64 KB
    __shared__ __align__(16) unsigned short Bs[2 * 16384];   // 64 KB

    int tid = threadIdx.x;
    int lane = tid & 63, w = tid >> 6;
    int quad = lane >> 4, l15 = lane & 15;

    int gx = gridDim.x;
    int nwg = gx * gridDim.y;
    int lin = blockIdx.y * gx + blockIdx.x;
    int swz = (lin & 7) * (nwg >> 3) + (lin >> 3);
    int bm = (swz / gx) * 256, bn = (swz % gx) * 256;

    int KT = K >> 6;

    int colswz = (((lane & 7) ^ ((lane >> 3) & 7)) << 3);
    int r0 = (w * 2) * 8 + (lane >> 3);
    int r1 = (w * 2 + 1) * 8 + (lane >> 3);
    const unsigned short* Ab0 = A + (size_t)(bm + r0) * K + colswz;
    const unsigned short* Ab1 = A + (size_t)(bm + r1) * K + colswz;
    const unsigned short* Bb0 = BT + (size_t)(bn + r0) * K + colswz;
    const unsigned short* Bb1 = BT + (size_t)(bn + r1) * K + colswz;
    size_t hK = (size_t)128 * K;

    unsigned short* dA0 = As + (w * 2) * 512;
    unsigned short* dA1 = As + (w * 2 + 1) * 512;
    unsigned short* dB0 = Bs + (w * 2) * 512;
    unsigned short* dB1 = Bs + (w * 2 + 1) * 512;

    auto stA = [&](int kt, int h, int bufp) __attribute__((always_inline)) {
        __builtin_amdgcn_global_load_lds(
            (__attribute__((address_space(1))) void*)(Ab0 + h * hK + (size_t)kt * 64),
            (__attribute__((address_space(3))) void*)(dA0 + bufp * 16384 + h * 8192), 16, 0, 0);
        __builtin_amdgcn_global_load_lds(
            (__attribute__((address_space(1))) void*)(Ab1 + h * hK + (size_t)kt * 64),
            (__attribute__((address_space(3))) void*)(dA1 + bufp * 16384 + h * 8192), 16, 0, 0);
    };
    auto stB = [&](int kt, int h, int bufp) __attribute__((always_inline)) {
        __builtin_amdgcn_global_load_lds(
            (__attribute__((address_space(1))) void*)(Bb0 + h * hK + (size_t)kt * 64),
            (__attribute__((address_space(3))) void*)(dB0 + bufp * 16384 + h * 8192), 16, 0, 0);
        __builtin_amdgcn_global_load_lds(
            (__attribute__((address_space(1))) void*)(Bb1 + h * hK + (size_t)kt * 64),
            (__attribute__((address_space(3))) void*)(dB1 + bufp * 16384 + h * 8192), 16, 0, 0);
    };

    int ards = (w >> 2) * 8192;
    int brds = (w & 3) * 4096;
    int rowb = l15 * 64;
    int swA = l15 & 7;
    int cof0 = ((quad) ^ swA) << 3;
    int cof1 = ((4 + quad) ^ swA) << 3;

    float4v acc[8][4];
#pragma unroll
    for (int i = 0; i < 8; ++i)
#pragma unroll
        for (int j = 0; j < 4; ++j) acc[i][j] = (float4v)0.f;

    stA(0, 0, 0); stA(0, 1, 0); stB(0, 0, 0); stB(0, 1, 0);
    stA(1, 0, 1); stA(1, 1, 1);
    asm volatile("s_waitcnt vmcnt(4)" ::: "memory");
    __builtin_amdgcn_s_barrier();
    asm volatile("" ::: "memory");

    auto ktile = [&](int kt, int bufp) __attribute__((always_inline)) {
        bool sB = (kt + 1) < KT;
        bool sA = (kt + 2) < KT;
        const unsigned short* ab = As + bufp * 16384 + ards + rowb;
        const unsigned short* bb = Bs + bufp * 16384 + brds + rowb;
        short8 afl[2][4], afh[2][4], bfa[2][2], bfb[2][2];

#pragma unroll
        for (int mi = 0; mi < 4; ++mi) {
            afl[0][mi] = *(const short8*)&ab[mi * 1024 + cof0];
            afl[1][mi] = *(const short8*)&ab[mi * 1024 + cof1];
        }
#pragma unroll
        for (int ni = 0; ni < 2; ++ni) {
            bfa[0][ni] = *(const short8*)&bb[ni * 1024 + cof0];
            bfa[1][ni] = *(const short8*)&bb[ni * 1024 + cof1];
        }
        if (sB) stB(kt + 1, 0, bufp ^ 1);
        GSYNC_IN();
#pragma unroll
        for (int kk = 0; kk < 2; ++kk)
#pragma unroll
            for (int mi = 0; mi < 4; ++mi)
#pragma unroll
                for (int ni = 0; ni < 2; ++ni)
                    acc[mi][ni] = __builtin_amdgcn_mfma_f32_16x16x32_bf16(afl[kk][mi], bfa[kk][ni], acc[mi][ni], 0, 0, 0);
        GSYNC_OUT();

#pragma unroll
        for (int mi = 0; mi < 4; ++mi) {
            afh[0][mi] = *(const short8*)&ab[(4 + mi) * 1024 + cof0];
            afh[1][mi] = *(const short8*)&ab[(4 + mi) * 1024 + cof1];
        }
#pragma unroll
        for (int ni = 0; ni < 2; ++ni) {
            bfb[0][ni] = *(const short8*)&bb[(2 + ni) * 1024 + cof0];
            bfb[1][ni] = *(const short8*)&bb[(2 + ni) * 1024 + cof1];
        }
        if (sB) stB(kt + 1, 1, bufp ^ 1);
        GSYNC_IN();
#pragma unroll
        for (int kk = 0; kk < 2; ++kk)
#pragma unroll
            for (int mi = 0; mi < 4; ++mi)
#pragma unroll
                for (int ni = 0; ni < 2; ++ni)
                    acc[mi][2 + ni] = __builtin_amdgcn_mfma_f32_16x16x32_bf16(afl[kk][mi], bfb[kk][ni], acc[mi][2 + ni], 0, 0, 0);
        GSYNC_OUT();

#pragma unroll
        for (int ni = 0; ni < 2; ++ni) {
            bfa[0][ni] = *(const short8*)&bb[ni * 1024 + cof0];
            bfa[1][ni] = *(const short8*)&bb[ni * 1024 + cof1];
        }
        if (sA) stA(kt + 2, 0, bufp);
        GSYNC_IN();
#pragma unroll
        for (int kk = 0; kk < 2; ++kk)
#pragma unroll
            for (int mi = 0; mi < 4; ++mi)
#pragma unroll
                for (int ni = 0; ni < 2; ++ni)
                    acc[4 + mi][ni] = __builtin_amdgcn_mfma_f32_16x16x32_bf16(afh[kk][mi], bfa[kk][ni], acc[4 + mi][ni], 0, 0, 0);
        GSYNC_OUT();

#pragma unroll
        for (int ni = 0; ni < 2; ++ni) {
            bfb[0][ni] = *(const short8*)&bb[(2 + ni) * 1024 + cof0];
            bfb[1][ni] = *(const short8*)&bb[(2 + ni) * 1024 + cof1];
        }
        if (sA) stA(kt + 2, 1, bufp);
        GSYNC_IN();
#pragma unroll
        for (int kk = 0; kk < 2; ++kk)
#pragma unroll
            for (int mi = 0; mi < 4; ++mi)
#pragma unroll
                for (int ni = 0; ni < 2; ++ni)
                    acc[4 + mi][2 + ni] = __builtin_amdgcn_mfma_f32_16x16x32_bf16(afh[kk][mi], bfb[kk][ni], acc[4 + mi][2 + ni], 0, 0, 0);
        GSYNC_OUT_KT();
    };

    for (int kt = 0; kt < KT; kt += 2) {
        ktile(kt, 0);
        ktile(kt + 1, 1);
    }

    int wm = (w >> 2) * 128, wn = (w & 3) * 64;
#pragma unroll
    for (int mi = 0; mi < 8; ++mi)
#pragma unroll
        for (int ni = 0; ni < 4; ++ni)
#pragma unroll
            for (int reg = 0; reg < 4; ++reg) {
                int row = bm + wm + mi * 16 + quad * 4 + reg;
                int col = bn + wn + ni * 16 + l15;
                float v = acc[mi][ni][reg];
                if (out_fp32) ((float*)Cout)[(size_t)row * N + col] = v;
                else ((unsigned short*)Cout)[(size_t)row * N + col] = f2bf(v);
            }
}

// ---------------------------------------------------------------------------
// 128x128 bf16 MFMA GEMM (R7 form) — used for O-proj (full-chip 512 blocks).
// ---------------------------------------------------------------------------
__global__ __launch_bounds__(256, 2) void gemm128(const unsigned short* __restrict__ A,
                                                  const unsigned short* __restrict__ BT,
                                                  void* __restrict__ Cout,
                                                  int M, int N, int K, int out_fp32)
{
    __shared__ __align__(16) unsigned short As[2 * 8192];   // 32 KB
    __shared__ __align__(16) unsigned short Bs[2 * 8192];   // 32 KB

    int tid = threadIdx.x;
    int lane = tid & 63, w = tid >> 6;
    int quad = lane >> 4, l15 = lane & 15;

    int gx = gridDim.x;
    int nwg = gx * gridDim.y;
    int lin = blockIdx.y * gx + blockIdx.x;
    int swz = (lin & 7) * (nwg >> 3) + (lin >> 3);
    int bm = (swz / gx) * 128, bn = (swz % gx) * 128;

    int KT = K >> 6;

    int colswz = (((lane & 7) ^ ((lane >> 3) & 7)) << 3);
    int r0 = w * 32 + (lane >> 3);
    const unsigned short* Ab = A + (size_t)(bm + r0) * K + colswz;
    const unsigned short* Bb = BT + (size_t)(bn + r0) * K + colswz;
    size_t rowK8 = (size_t)8 * K;

    unsigned short* dA = As + w * 2048;
    unsigned short* dB = Bs + w * 2048;

    auto stA = [&](int kt, int bufp) __attribute__((always_inline)) {
#pragma unroll
        for (int i = 0; i < 4; ++i)
            __builtin_amdgcn_global_load_lds(
                (__attribute__((address_space(1))) void*)(Ab + (size_t)i * rowK8 + (size_t)kt * 64),
                (__attribute__((address_space(3))) void*)(dA + bufp * 8192 + i * 512), 16, 0, 0);
    };
    auto stB = [&](int kt, int bufp) __attribute__((always_inline)) {
#pragma unroll
        for (int i = 0; i < 4; ++i)
            __builtin_amdgcn_global_load_lds(
                (__attribute__((address_space(1))) void*)(Bb + (size_t)i * rowK8 + (size_t)kt * 64),
                (__attribute__((address_space(3))) void*)(dB + bufp * 8192 + i * 512), 16, 0, 0);
    };

    int wm = (w >> 1) * 64, wn = (w & 1) * 64;
    int swk = l15 & 7;
    int cof0 = ((quad) ^ swk) << 3;
    int cof1 = ((4 + quad) ^ swk) << 3;
    const int arow = (wm + l15) * 64;
    const int brow = (wn + l15) * 64;

    float4v acc[4][4];
#pragma unroll
    for (int i = 0; i < 4; ++i)
#pragma unroll
        for (int j = 0; j < 4; ++j) acc[i][j] = (float4v)0.f;

    stA(0, 0); stB(0, 0);
    stA(1, 1);
    asm volatile("s_waitcnt vmcnt(4)" ::: "memory");
    __builtin_amdgcn_s_barrier();
    asm volatile("" ::: "memory");

    auto ktile = [&](int kt, int bufp) __attribute__((always_inline)) {
        const unsigned short* ab = As + bufp * 8192 + arow;
        const unsigned short* bb = Bs + bufp * 8192 + brow;
        short8 af[2][4], bf[2][4];

        if (kt + 1 < KT) stB(kt + 1, bufp ^ 1);
#pragma unroll
        for (int mi = 0; mi < 4; ++mi) {
            af[0][mi] = *(const short8*)&ab[mi * 1024 + cof0];
            af[1][mi] = *(const short8*)&ab[mi * 1024 + cof1];
        }
#pragma unroll
        for (int ni = 0; ni < 4; ++ni) {
            bf[0][ni] = *(const short8*)&bb[ni * 1024 + cof0];
            bf[1][ni] = *(const short8*)&bb[ni * 1024 + cof1];
        }
        __builtin_amdgcn_s_setprio(1);
#pragma unroll
        for (int kk = 0; kk < 2; ++kk)
#pragma unroll
            for (int mi = 0; mi < 4; ++mi)
#pragma unroll
                for (int ni = 0; ni < 2; ++ni)
                    acc[mi][ni] = __builtin_amdgcn_mfma_f32_16x16x32_bf16(af[kk][mi], bf[kk][ni], acc[mi][ni], 0, 0, 0);
        __builtin_amdgcn_s_setprio(0);
        asm volatile("s_waitcnt lgkmcnt(0)" ::: "memory");
        __builtin_amdgcn_sched_barrier(0);
        __builtin_amdgcn_s_barrier();
        asm volatile("" ::: "memory");

        bool sA = (kt + 2) < KT;
        if (sA) stA(kt + 2, bufp);
        __builtin_amdgcn_s_setprio(1);
#pragma unroll
        for (int kk = 0; kk < 2; ++kk)
#pragma unroll
            for (int mi = 0; mi < 4; ++mi)
#pragma unroll
                for (int ni = 2; ni < 4; ++ni)
                    acc[mi][ni] = __builtin_amdgcn_mfma_f32_16x16x32_bf16(af[kk][mi], bf[kk][ni], acc[mi][ni], 0, 0, 0);
        __builtin_amdgcn_s_setprio(0);
        if (sA) asm volatile("s_waitcnt vmcnt(4)" ::: "memory");
        else    asm volatile("s_waitcnt vmcnt(0)" ::: "memory");
        __builtin_amdgcn_sched_barrier(0);
        __builtin_amdgcn_s_barrier();
        asm volatile("" ::: "memory");
    };

    for (int kt = 0; kt < KT; kt += 2) {
        ktile(kt, 0);
        ktile(kt + 1, 1);
    }

#pragma unroll
    for (int mi = 0; mi < 4; ++mi)
#pragma unroll
        for (int ni = 0; ni < 4; ++ni)
#pragma unroll
            for (int reg = 0; reg < 4; ++reg) {
                int row = bm + wm + mi * 16 + quad * 4 + reg;
                int col = bn + wn + ni * 16 + l15;
                float v = acc[mi][ni][reg];
                if (out_fp32) ((float*)Cout)[(size_t)row * N + col] = v;
                else ((unsigned short*)Cout)[(size_t)row * N + col] = f2bf(v);
            }
}

// ---------------------------------------------------------------------------
// post: fused norm_rope (Q in-place, K -> Kall) + K-cache fill + V transpose
// ---------------------------------------------------------------------------
__global__ __launch_bounds__(256) void post(unsigned short* __restrict__ QKVh,
                                            unsigned short* __restrict__ Kall,
                                            unsigned short* __restrict__ Vt,
                                            const float* __restrict__ qw,
                                            const float* __restrict__ kw,
                                            const int* __restrict__ seg,
                                            const int* __restrict__ meta,
                                            const int* __restrict__ cur_ptr,
                                            const float* __restrict__ kc,
                                            const float* __restrict__ vc)
{
    int id = blockIdx.x;
    int tid = threadIdx.x;
    int cur = cur_ptr[0];

    if (id < 24576) {   // norm + rope
        int rowid = id * 4 + (tid >> 6);
        int lane = tid & 63;
        int hh = rowid % 24;
        int bt = rowid / 24;
        int t = bt & (Tc - 1);
        int b = bt >> 11;

        const unsigned short* in;
        unsigned short* out;
        const float* wt;
        if (hh < 16) {
            unsigned short* p = QKVh + (size_t)bt * 4096 + hh * Hc;
            in = p; out = p; wt = qw;
        } else {
            int kh = hh - 16;
            in = QKVh + (size_t)bt * 4096 + 2048 + kh * Hc;
            out = Kall + (((size_t)b * Sc + cur + t) * KHc + kh) * Hc;
            wt = kw;
        }
        float v1 = bf2f(in[lane]), v2 = bf2f(in[lane + 64]);
        float ssq = v1 * v1 + v2 * v2;
#pragma unroll
        for (int off = 1; off < 64; off <<= 1) ssq += __shfl_xor(ssq, off);
        float rinv = rsqrtf(ssq * (1.0f / Hc) + EPSc);

        int sg = seg[bt];
        long long pos = (sg != 0) ? (long long)(t - meta[b]) : (long long)(1 << 30);
        float posf = (float)(pos + (long long)cur);
        float inv_freq = exp2f(-(float)lane * (19.931568569324174f / 64.0f));
        float s, c;
        sincosf(posf * inv_freq, &s, &c);

        float n1 = wt[lane] * v1 * rinv;
        float n2 = wt[lane + 64] * v2 * rinv;
        out[lane]      = f2bf(n1 * c - n2 * s);
        out[lane + 64] = f2bf(n2 * c + n1 * s);
        return;
    }
    id -= 24576;
    if (id < 2048) {   // K cache fill
        size_t base = ((size_t)id * 256 + tid) * 8;
        int s = (int)((base >> 10) & (Sc - 1));
        if (s >= cur && s < cur + Tc) return;
        float4 a = *(const float4*)&kc[base];
        float4 b = *(const float4*)&kc[base + 4];
        U16x8 o;
        o.us[0] = f2bf(a.x); o.us[1] = f2bf(a.y); o.us[2] = f2bf(a.z); o.us[3] = f2bf(a.w);
        o.us[4] = f2bf(b.x); o.us[5] = f2bf(b.y); o.us[6] = f2bf(b.z); o.us[7] = f2bf(b.w);
        *(uint4*)&Kall[base] = o.u;
        return;
    }
    id -= 2048;
    {   // V transpose -> f16
        int gid = id * 256 + tid;
        int h  = gid & 127;
        int s8 = ((gid >> 7) & 255) * 8;
        int kh = (gid >> 15) & 7;
        int b  = gid >> 18;
        int curT = cur + Tc;
        unsigned short tmp[8];
#pragma unroll
        for (int e = 0; e < 8; ++e) {
            int s = s8 + e;
            float f;
            if (s >= cur && s < curT)
                f = bf2f(QKVh[(size_t)(b * Tc + (s - cur)) * 4096 + 3072 + kh * Hc + h]);
            else
                f = vc[((size_t)(b * Sc + s) * KHc + kh) * Hc + h];
            tmp[e] = __half_as_ushort(__float2half(f));
        }
        *(uint4*)&Vt[(((size_t)b * KHc + kh) * Hc + h) * Sc + s8] = *(uint4*)tmp;
    }
}

// ---------------------------------------------------------------------------
// MFMA flash attention, S^T formulation — 8-wave version (R3, proven).
// ---------------------------------------------------------------------------
__global__ __launch_bounds__(512, 4) void flash_mfma(const unsigned short* __restrict__ Qb,
                                                     const unsigned short* __restrict__ Kall,
                                                     const unsigned short* __restrict__ Vt,
                                                     const int* __restrict__ seg,
                                                     const int* __restrict__ meta,
                                                     const int* __restrict__ cur_ptr,
                                                     unsigned short* __restrict__ Ob)
{
    __shared__ __align__(16) unsigned short Ks[64 * 128];   // bf16 [s][h], swizzled
    __shared__ __align__(16) unsigned short Vs[128 * 64];   // f16  [h][s], swizzled
    __shared__ __align__(16) unsigned short Ps[128 * 64];   // f16  [q][s], XOR-swizzled

    int tid = threadIdx.x;
    int lane = tid & 63, w = tid >> 6;          // w in 0..7
    int quad = lane >> 4, l15 = lane & 15;
    int bid = blockIdx.x;
    int raw = bid & 15;
    int n  = (bid >> 4) & 15;
    int b  = bid >> 8;
    int qt = (b == 0) ? raw : (15 - raw);
    int kh = n >> 1;
    int cur = cur_ptr[0];
    int startb = meta[Bc + b];
    int curT = cur + Tc;
    int t0 = qt * 128 + w * 16;                 // this wave's 16 q-rows

    short8 qf[4];
#pragma unroll
    for (int ks = 0; ks < 4; ++ks) {
        int row = t0 + l15;
        U16x8 uq;
        uq.u = *(const uint4*)&Qb[(size_t)(b * Tc + row) * 4096 + n * Hc + ks * 32 + quad * 8];
        qf[ks] = uq.s8;
    }

    int trow0 = t0 + l15;
    int sg0 = seg[b * Tc + trow0];
    int cls = (sg0 == 0) ? 0 : ((sg0 == 1) ? 1 : 2);
    int ct  = cur + trow0;
    unsigned long long mball = __ballot(cls == 1);
    bool allseg1 = (mball == 0xFFFFFFFFFFFFFFFFull);

    float lsum = 0.f;
    float4v oT[8];
#pragma unroll
    for (int i = 0; i < 8; ++i) oT[i] = (float4v)0.f;

    int s_end = min(Sc, cur + qt * 128 + 128);
    int nch = (s_end + 63) >> 6;

    const size_t kstride = (size_t)KHc * Hc;
    const unsigned short* kptr[2];
    unsigned short* kdst[2];
#pragma unroll
    for (int i = 0; i < 2; ++i) {
        int j = w * 2 + i;
        int row = j * 4 + (lane >> 4);
        int pl = lane & 15;
        int pg = pl ^ ((row >> 1) & 7);
        kptr[i] = Kall + (size_t)b * Sc * kstride + (size_t)row * kstride + kh * Hc + pg * 8;
        kdst[i] = Ks + j * 512;
    }
    const unsigned short* vptr[2];
    unsigned short* vdst[2];
#pragma unroll
    for (int i = 0; i < 2; ++i) {
        int j = w * 2 + i;
        int h = j * 8 + (lane >> 3);
        int pl = lane & 7;
        int pg = pl ^ ((h >> 1) & 7);
        vptr[i] = Vt + ((size_t)b * KHc + kh) * (size_t)Hc * Sc + (size_t)h * Sc + pg * 8;
        vdst[i] = Vs + j * 512;
    }
    int sw3 = (l15 >> 1) & 7;
    int sw8 = l15 & 7;
    unsigned short* psrow = Ps + (w * 16 + l15) * 64;

    for (int c = 0; c < nch; ++c) {
        int s0 = c * 64;
#pragma unroll
        for (int i = 0; i < 2; ++i) {
            __builtin_amdgcn_global_load_lds(
                (__attribute__((address_space(1))) void*)(kptr[i] + (size_t)s0 * kstride),
                (__attribute__((address_space(3))) void*)kdst[i], 16, 0, 0);
            __builtin_amdgcn_global_load_lds(
                (__attribute__((address_space(1))) void*)(vptr[i] + s0),
                (__attribute__((address_space(3))) void*)vdst[i], 16, 0, 0);
        }
        __syncthreads();

        float4v st[4];
#pragma unroll
        for (int i = 0; i < 4; ++i) st[i] = (float4v)0.f;
        __builtin_amdgcn_s_setprio(1);
#pragma unroll
        for (int ks = 0; ks < 4; ++ks) {
#pragma unroll
            for (int stile = 0; stile < 4; ++stile) {
                short8 kf = *(const short8*)&Ks[(stile * 16 + l15) * 128 + ((ks * 4 + quad) ^ sw3) * 8];
                st[stile] = __builtin_amdgcn_mfma_f32_16x16x32_bf16(kf, qf[ks], st[stile], 0, 0, 0);
            }
        }
        __builtin_amdgcn_s_setprio(0);

        bool fullok = allseg1 && (s0 >= startb) && (s0 + 63 <= cur + t0) && (s0 + 63 < curT);

#pragma unroll
        for (int stile = 0; stile < 4; ++stile) {
            float p0, p1, p2, p3;
            if (fullok) {
                p0 = exp2f(st[stile][0] * SCALE2);
                p1 = exp2f(st[stile][1] * SCALE2);
                p2 = exp2f(st[stile][2] * SCALE2);
                p3 = exp2f(st[stile][3] * SCALE2);
            } else {
                float pp[4];
#pragma unroll
                for (int reg = 0; reg < 4; ++reg) {
                    int s = s0 + stile * 16 + quad * 4 + reg;
                    int kvseg = (s >= startb && s < curT) ? 1 : 0;
                    bool ok = (s <= ct) && (cls == kvseg);
                    pp[reg] = exp2f(ok ? st[stile][reg] * SCALE2 : -1e30f);
                }
                p0 = pp[0]; p1 = pp[1]; p2 = pp[2]; p3 = pp[3];
            }
            lsum += (p0 + p1) + (p2 + p3);
            H2U a, d;
            a.h = __builtin_amdgcn_cvt_pkrtz(p0, p1);
            d.h = __builtin_amdgcn_cvt_pkrtz(p2, p3);
            uint2 pk; pk.x = a.u; pk.y = d.u;
            *(uint2*)&psrow[(((stile * 2 + (quad >> 1)) ^ sw8) << 3) + (quad & 1) * 4] = pk;
        }

        __builtin_amdgcn_s_setprio(1);
#pragma unroll
        for (int kk = 0; kk < 2; ++kk) {
            S8H8 pf;
            pf.s = *(const short8*)&psrow[((kk * 4 + quad) ^ sw8) << 3];
#pragma unroll
            for (int htile = 0; htile < 8; ++htile) {
                S8H8 vf;
                vf.s = *(const short8*)&Vs[(htile * 16 + l15) * 64 + ((kk * 4 + quad) ^ sw3) * 8];
                oT[htile] = __builtin_amdgcn_mfma_f32_16x16x32_f16(vf.h, pf.h, oT[htile], 0, 0, 0);
            }
        }
        __builtin_amdgcn_s_setprio(0);

        __syncthreads();
    }

    float l = lsum;
    l += __shfl_xor(l, 16);
    l += __shfl_xor(l, 32);
    float linv = (l > 0.f) ? (1.0f / l) : 0.f;

    {
        int trow = t0 + l15;
        size_t base = ((size_t)(b * Tc + trow) * Nc + n) * Hc;
#pragma unroll
        for (int htile = 0; htile < 8; ++htile) {
            float4v v = oT[htile];
            unsigned short r0 = f2bf(v[0] * linv);
            unsigned short r1 = f2bf(v[1] * linv);
            unsigned short r2 = f2bf(v[2] * linv);
            unsigned short r3 = f2bf(v[3] * linv);
            uint2 pk;
            pk.x = (unsigned)r0 | ((unsigned)r1 << 16);
            pk.y = (unsigned)r2 | ((unsigned)r3 << 16);
            *(uint2*)&Ob[base + htile * 16 + quad * 4] = pk;
        }
    }
}

// ---------------------------------------------------------------------------
extern "C" void kernel_launch(void* const* d_in, const int* in_sizes, int n_in,
                              void* d_out, int out_size, void* d_ws, size_t ws_size,
                              hipStream_t stream)
{
    const float* x        = (const float*)d_in[0];
    const float* q_w      = (const float*)d_in[1];
    const float* k_w      = (const float*)d_in[2];
    const float* v_w      = (const float*)d_in[3];
    const float* o_w      = (const float*)d_in[4];
    const float* q_norm_w = (const float*)d_in[5];
    const float* k_norm_w = (const float*)d_in[6];
    const float* k_cache  = (const float*)d_in[7];
    const float* v_cache  = (const float*)d_in[8];
    const int*   seg      = (const int*)d_in[9];
    const int*   startind = (const int*)d_in[10];
    const int*   cur_ptr  = (const int*)d_in[11];
    (void)in_sizes; (void)n_in; (void)out_size; (void)ws_size;

    char* base = (char*)d_ws;
    int* meta = (int*)base;                                          //      1024 B
    unsigned short* QKVh = (unsigned short*)(base + 1024);           // 33.55 MB [4096][4096]
    unsigned short* Kall = (unsigned short*)(base + 33555456);       //  8.39 MB bf16 [B][S][KH][H]
    unsigned short* Vt   = (unsigned short*)(base + 41944064);       //  8.39 MB f16  [B][KH][H][S]
    unsigned short* xb   = (unsigned short*)(base + 50332672);       // 16.78 MB; reused as Ob
    unsigned short* qkvwT= (unsigned short*)(base + 67109888);       // 16.78 MB [4096][2048]
    unsigned short* owT  = (unsigned short*)(base + 83887104);       //  8.39 MB [2048][2048]
    unsigned short* Ob   = xb;

    // 1) fused prep: meta + cast + 4 transposes (vectorized writes)
    prep<<<Bc + 4096 + 4096 + 2048 + 2048 + 4096, 256, 0, stream>>>(
        x, q_w, k_w, v_w, o_w, seg, startind, meta, xb, qkvwT, owT);

    // 2) fused QKV projection: 256^2 8-phase (best measured: 78.9 us)
    gemm256<<<dim3(16, 16), 512, 0, stream>>>(xb, qkvwT, QKVh, Bc * Tc, 4096, Dc, 0);

    // 3) fused post: norm+rope, K-cache fill, V transpose (f16)
    post<<<24576 + 2048 + 2048, 256, 0, stream>>>(QKVh, Kall, Vt,
        q_norm_w, k_norm_w, seg, meta, cur_ptr, k_cache, v_cache);

    // 4) flash attention: 128-row tiles, 8-wave blocks
    flash_mfma<<<Bc * Nc * (Tc / 128), 512, 0, stream>>>(QKVh, Kall, Vt, seg, meta, cur_ptr, Ob);

    // 5) O projection: 128^2, full-chip 512 blocks (2 blk/CU)
    gemm128<<<dim3(16, 32), 256, 0, stream>>>(Ob, owT, d_out, Bc * Tc, Dc, Nc * Hc, 1);
}